// Round 1
// baseline (711.545 us; speedup 1.0000x reference)
//
#include <hip/hip_runtime.h>
#include <hip/hip_bf16.h>

#define BT 4096        // B*T rows
#define TT 1024        // T
#define HN 16          // heads

typedef __attribute__((ext_vector_type(8))) short bf16x8;
typedef __attribute__((ext_vector_type(4))) float f32x4;

__device__ __forceinline__ unsigned short f2bf(float f) {
    unsigned u = __builtin_bit_cast(unsigned, f);
    unsigned r = (u + 0x7fffu + ((u >> 16) & 1u)) >> 16;
    return (unsigned short)r;
}

__device__ __forceinline__ void g2l16(const void* g, void* l) {
    __builtin_amdgcn_global_load_lds(
        (__attribute__((address_space(1))) void*)(g),
        (__attribute__((address_space(3))) void*)(l), 16, 0, 0);
}

// ---------------------------------------------------------------- transpose+cast
// W [K x N] f32  ->  Wt [N x K] bf16
__global__ __launch_bounds__(256)
void transpose_cast(const float* __restrict__ W, unsigned short* __restrict__ Wt,
                    int K, int N)
{
    __shared__ float tile[32][33];
    int n0 = blockIdx.x * 32, k0 = blockIdx.y * 32;
    int tx = threadIdx.x, ty = threadIdx.y;
#pragma unroll
    for (int i = ty; i < 32; i += 8)
        tile[i][tx] = W[(size_t)(k0 + i) * N + n0 + tx];
    __syncthreads();
#pragma unroll
    for (int i = ty; i < 32; i += 8)
        Wt[(size_t)(n0 + i) * K + k0 + tx] = f2bf(tile[tx][i]);
}

// ---------------------------------------------------------------- f32 -> bf16 cast
__global__ __launch_bounds__(256)
void cast_bf16(const float* __restrict__ in, unsigned short* __restrict__ out)
{
    int i = blockIdx.x * 256 + threadIdx.x;
    float4 v = ((const float4*)in)[i];
    ushort4 o;
    o.x = f2bf(v.x); o.y = f2bf(v.y); o.z = f2bf(v.z); o.w = f2bf(v.w);
    ((ushort4*)out)[i] = o;
}

// ---------------------------------------------------------------- LayerNorm (C=1024)
// one block per row; 256 threads x float4
__global__ __launch_bounds__(256)
void ln_kernel(const float* __restrict__ x, const float* __restrict__ g,
               const float* __restrict__ bta, unsigned short* __restrict__ out)
{
    __shared__ float red[8];
    int row = blockIdx.x;
    const float* xr = x + (size_t)row * 1024;
    float4 v = ((const float4*)xr)[threadIdx.x];
    float s = v.x + v.y + v.z + v.w;
    float q = v.x*v.x + v.y*v.y + v.z*v.z + v.w*v.w;
#pragma unroll
    for (int m = 1; m < 64; m <<= 1) {
        s += __shfl_xor(s, m, 64);
        q += __shfl_xor(q, m, 64);
    }
    int wave = threadIdx.x >> 6;
    if ((threadIdx.x & 63) == 0) { red[wave] = s; red[4 + wave] = q; }
    __syncthreads();
    s = red[0] + red[1] + red[2] + red[3];
    q = red[4] + red[5] + red[6] + red[7];
    float mean = s * (1.f / 1024.f);
    float var  = q * (1.f / 1024.f) - mean * mean;
    float rstd = rsqrtf(var + 1e-5f);
    float4 gv = ((const float4*)g)[threadIdx.x];
    float4 bv = ((const float4*)bta)[threadIdx.x];
    ushort4 o;
    o.x = f2bf((v.x - mean) * rstd * gv.x + bv.x);
    o.y = f2bf((v.y - mean) * rstd * gv.y + bv.y);
    o.z = f2bf((v.z - mean) * rstd * gv.z + bv.z);
    o.w = f2bf((v.w - mean) * rstd * gv.w + bv.w);
    ((ushort4*)(out + (size_t)row * 1024))[threadIdx.x] = o;
}

// ---------------------------------------------------------------- GEMM (m97 structure)
// C[M,N] = A[M,K](bf16) * Bt[N,K](bf16)^T + bias
// MODE 0: out bf16        MODE 1: out bf16, gelu     MODE 2: out f32, + res
template<int MODE>
__global__ __launch_bounds__(256)
void gemm_bt(const unsigned short* __restrict__ A,
             const unsigned short* __restrict__ Bt,
             const float* __restrict__ bias,
             const float* __restrict__ res,
             void* __restrict__ outp,
             int M, int N, int K)
{
    __shared__ unsigned short lA[128 * 64];
    __shared__ unsigned short lB[128 * 64];
    const int tid = threadIdx.x;
    const int wave = tid >> 6, lane = tid & 63;
    const int quad = lane >> 4, l16 = lane & 15;
    const int m0 = blockIdx.y * 128, n0 = blockIdx.x * 128;
    const int wrow = (wave >> 1) * 64, wcol = (wave & 1) * 64;

    f32x4 acc[4][4];
#pragma unroll
    for (int i = 0; i < 4; ++i)
#pragma unroll
        for (int j = 0; j < 4; ++j)
#pragma unroll
            for (int r = 0; r < 4; ++r) acc[i][j][r] = 0.f;

    for (int k0 = 0; k0 < K; k0 += 64) {
        __syncthreads();
#pragma unroll
        for (int it = 0; it < 4; ++it) {
            int chunk = it * 256 + tid;
            int row = chunk >> 3, kc = chunk & 7;
            g2l16(A  + (size_t)(m0 + row) * K + k0 + kc * 8, &lA[chunk * 8]);
            g2l16(Bt + (size_t)(n0 + row) * K + k0 + kc * 8, &lB[chunk * 8]);
        }
        __syncthreads();
#pragma unroll
        for (int kk = 0; kk < 64; kk += 32) {
            bf16x8 af[4], bfr[4];
#pragma unroll
            for (int i = 0; i < 4; ++i)
                af[i] = *(const bf16x8*)&lA[(wrow + i * 16 + l16) * 64 + kk + quad * 8];
#pragma unroll
            for (int j = 0; j < 4; ++j)
                bfr[j] = *(const bf16x8*)&lB[(wcol + j * 16 + l16) * 64 + kk + quad * 8];
#pragma unroll
            for (int i = 0; i < 4; ++i)
#pragma unroll
                for (int j = 0; j < 4; ++j)
                    acc[i][j] = __builtin_amdgcn_mfma_f32_16x16x32_bf16(af[i], bfr[j], acc[i][j], 0, 0, 0);
        }
    }

#pragma unroll
    for (int i = 0; i < 4; ++i) {
#pragma unroll
        for (int r = 0; r < 4; ++r) {
            int m = m0 + wrow + i * 16 + quad * 4 + r;
#pragma unroll
            for (int j = 0; j < 4; ++j) {
                int n = n0 + wcol + j * 16 + l16;
                float v = acc[i][j][r] + bias[n];
                if (MODE == 1) v = 0.5f * v * (1.f + erff(v * 0.70710678118654752f));
                size_t idx = (size_t)m * N + n;
                if (MODE == 2) ((float*)outp)[idx] = v + res[idx];
                else ((unsigned short*)outp)[idx] = f2bf(v);
            }
        }
    }
}

// ---------------------------------------------------------------- flash attention
// grid: (T/128, B*H). 4 waves; wave owns 32 q rows. D=64. bf16 in/out.
// K LDS [key][d] stride 72 (pad), V LDS transposed [d][key] stride 72,
// P per-wave [32][72]. Online softmax in registers, C-layout.
__global__ __launch_bounds__(256)
void attn_kernel(const unsigned short* __restrict__ qp,
                 const unsigned short* __restrict__ kp,
                 const unsigned short* __restrict__ vp,
                 unsigned short* __restrict__ op,
                 int qstride, int kstride, int causal)
{
    __shared__ unsigned short lK[64 * 72];
    __shared__ unsigned short lV[64 * 72];
    __shared__ unsigned short lP[4][32 * 72];

    const int tid = threadIdx.x;
    const int wave = tid >> 6, lane = tid & 63;
    const int quad = lane >> 4, l16 = lane & 15;
    const int bh = blockIdx.y, b = bh >> 4, h = bh & 15;
    const int q0 = blockIdx.x * 128;
    const size_t rowbase = (size_t)b * TT;
    const int hoff = h * 64;

    // Q fragments, held in registers for the whole K loop
    bf16x8 qf[2][2];
#pragma unroll
    for (int i = 0; i < 2; ++i) {
        int qrow = q0 + wave * 32 + i * 16 + l16;
        const unsigned short* qrp = qp + (rowbase + qrow) * (size_t)qstride + hoff;
#pragma unroll
        for (int kk = 0; kk < 2; ++kk)
            qf[i][kk] = *(const bf16x8*)(qrp + kk * 32 + quad * 8);
    }

    f32x4 oacc[2][4];
    float mrun[2][4], lrun[2][4];
#pragma unroll
    for (int i = 0; i < 2; ++i)
#pragma unroll
        for (int r = 0; r < 4; ++r) {
            mrun[i][r] = -1e30f; lrun[i][r] = 0.f;
#pragma unroll
            for (int jd = 0; jd < 4; ++jd) oacc[i][jd][r] = 0.f;
        }

    const int nkt = causal ? (q0 / 64 + 2) : (TT / 64);
    for (int kt = 0; kt < nkt; ++kt) {
        __syncthreads();
        // stage K tile [key][d] and V tile transposed [d][key]
#pragma unroll
        for (int it = 0; it < 2; ++it) {
            int c = it * 256 + tid;
            int key = c >> 3, dc = c & 7;
            size_t goff = (rowbase + kt * 64 + key) * (size_t)kstride + hoff + dc * 8;
            bf16x8 tk = *(const bf16x8*)(kp + goff);
            *(bf16x8*)&lK[key * 72 + dc * 8] = tk;
            bf16x8 tv = *(const bf16x8*)(vp + goff);
#pragma unroll
            for (int j = 0; j < 8; ++j)
                lV[(dc * 8 + j) * 72 + key] = ((unsigned short*)&tv)[j];
        }
        __syncthreads();

        // S = Q K^T  (wave-private 32x64 block, C-layout)
        f32x4 s[2][4];
#pragma unroll
        for (int i = 0; i < 2; ++i)
#pragma unroll
            for (int j = 0; j < 4; ++j)
#pragma unroll
                for (int r = 0; r < 4; ++r) s[i][j][r] = 0.f;
#pragma unroll
        for (int kk = 0; kk < 2; ++kk) {
            bf16x8 bfr[4];
#pragma unroll
            for (int j = 0; j < 4; ++j)
                bfr[j] = *(const bf16x8*)&lK[(j * 16 + l16) * 72 + kk * 32 + quad * 8];
#pragma unroll
            for (int i = 0; i < 2; ++i)
#pragma unroll
                for (int j = 0; j < 4; ++j)
                    s[i][j] = __builtin_amdgcn_mfma_f32_16x16x32_bf16(qf[i][kk], bfr[j], s[i][j], 0, 0, 0);
        }

        const bool domask = (causal != 0) && (kt * 64 + 63 > q0);
        // online softmax, per owned row (i,r); all 16 lanes of a quad agree
#pragma unroll
        for (int i = 0; i < 2; ++i)
#pragma unroll
            for (int r = 0; r < 4; ++r) {
                int qg = q0 + wave * 32 + i * 16 + quad * 4 + r;
#pragma unroll
                for (int j = 0; j < 4; ++j) {
                    float v = s[i][j][r] * 0.125f;
                    if (domask) {
                        int kg = kt * 64 + j * 16 + l16;
                        if (kg > qg) v = -1e30f;
                    }
                    s[i][j][r] = v;
                }
                float rmax = fmaxf(fmaxf(s[i][0][r], s[i][1][r]), fmaxf(s[i][2][r], s[i][3][r]));
                rmax = fmaxf(rmax, __shfl_xor(rmax, 1, 64));
                rmax = fmaxf(rmax, __shfl_xor(rmax, 2, 64));
                rmax = fmaxf(rmax, __shfl_xor(rmax, 4, 64));
                rmax = fmaxf(rmax, __shfl_xor(rmax, 8, 64));
                float mn = fmaxf(mrun[i][r], rmax);
                float alpha = __expf(mrun[i][r] - mn);
                mrun[i][r] = mn;
                float rs = 0.f;
#pragma unroll
                for (int j = 0; j < 4; ++j) {
                    float p = __expf(s[i][j][r] - mn);
                    s[i][j][r] = p;
                    rs += p;
                }
                rs += __shfl_xor(rs, 1, 64);
                rs += __shfl_xor(rs, 2, 64);
                rs += __shfl_xor(rs, 4, 64);
                rs += __shfl_xor(rs, 8, 64);
                lrun[i][r] = lrun[i][r] * alpha + rs;
#pragma unroll
                for (int jd = 0; jd < 4; ++jd) oacc[i][jd][r] *= alpha;
            }

        // P (C-layout regs) -> LDS (A-layout readable), bf16
        unsigned short* pw = lP[wave];
#pragma unroll
        for (int i = 0; i < 2; ++i)
#pragma unroll
            for (int j = 0; j < 4; ++j)
#pragma unroll
                for (int r = 0; r < 4; ++r)
                    pw[(i * 16 + quad * 4 + r) * 72 + j * 16 + l16] = f2bf(s[i][j][r]);

        // O += P V
#pragma unroll
        for (int kk = 0; kk < 2; ++kk) {
            bf16x8 pf[2], vf[4];
#pragma unroll
            for (int i = 0; i < 2; ++i)
                pf[i] = *(const bf16x8*)&pw[(i * 16 + l16) * 72 + kk * 32 + quad * 8];
#pragma unroll
            for (int jd = 0; jd < 4; ++jd)
                vf[jd] = *(const bf16x8*)&lV[(jd * 16 + l16) * 72 + kk * 32 + quad * 8];
#pragma unroll
            for (int i = 0; i < 2; ++i)
#pragma unroll
                for (int jd = 0; jd < 4; ++jd)
                    oacc[i][jd] = __builtin_amdgcn_mfma_f32_16x16x32_bf16(pf[i], vf[jd], oacc[i][jd], 0, 0, 0);
        }
    }

    // epilogue: O / l
#pragma unroll
    for (int i = 0; i < 2; ++i)
#pragma unroll
        for (int r = 0; r < 4; ++r) {
            int qg = q0 + wave * 32 + i * 16 + quad * 4 + r;
            float inv = 1.f / lrun[i][r];
            unsigned short* orow = op + (rowbase + qg) * (size_t)1024 + hoff;
#pragma unroll
            for (int jd = 0; jd < 4; ++jd)
                orow[jd * 16 + l16] = f2bf(oacc[i][jd][r] * inv);
        }
}

// ---------------------------------------------------------------- launch
extern "C" void kernel_launch(void* const* d_in, const int* in_sizes, int n_in,
                              void* d_out, int out_size, void* d_ws, size_t ws_size,
                              hipStream_t stream)
{
    const float* x     = (const float*)d_in[0];
    const float* ctx   = (const float*)d_in[1];
    const float* ln1_g = (const float*)d_in[2];
    const float* ln1_b = (const float*)d_in[3];
    const float* qkv_w = (const float*)d_in[4];
    const float* qkv_b = (const float*)d_in[5];
    const float* aow   = (const float*)d_in[6];
    const float* aob   = (const float*)d_in[7];
    const float* lnc_g = (const float*)d_in[8];
    const float* lnc_b = (const float*)d_in[9];
    const float* q_w   = (const float*)d_in[10];
    const float* q_b   = (const float*)d_in[11];
    const float* kv_w  = (const float*)d_in[12];
    const float* kv_b  = (const float*)d_in[13];
    const float* cow   = (const float*)d_in[14];
    const float* cob   = (const float*)d_in[15];
    const float* ln2_g = (const float*)d_in[16];
    const float* ln2_b = (const float*)d_in[17];
    const float* f1w   = (const float*)d_in[18];
    const float* f1b   = (const float*)d_in[19];
    const float* f2w   = (const float*)d_in[20];
    const float* f2b   = (const float*)d_in[21];

    char* ws = (char*)d_ws;
    size_t off = 0;
    auto alloc = [&](size_t bytes) {
        char* p = ws + off;
        off += (bytes + 255) & ~(size_t)255;
        return p;
    };

    unsigned short* WtQKV = (unsigned short*)alloc((size_t)3072 * 1024 * 2);
    unsigned short* WtAO  = (unsigned short*)alloc((size_t)1024 * 1024 * 2);
    unsigned short* WtQ   = (unsigned short*)alloc((size_t)1024 * 1024 * 2);
    unsigned short* WtKV  = (unsigned short*)alloc((size_t)2048 * 1024 * 2);
    unsigned short* WtCO  = (unsigned short*)alloc((size_t)1024 * 1024 * 2);
    unsigned short* WtF1  = (unsigned short*)alloc((size_t)4096 * 1024 * 2);
    unsigned short* WtF2  = (unsigned short*)alloc((size_t)1024 * 4096 * 2);
    unsigned short* hA    = (unsigned short*)alloc((size_t)BT * 1024 * 2);
    unsigned short* ctxb  = (unsigned short*)alloc((size_t)BT * 1024 * 2);
    unsigned short* qkvb  = (unsigned short*)alloc((size_t)BT * 3072 * 2);
    unsigned short* o1    = (unsigned short*)alloc((size_t)BT * 1024 * 2);
    float*          x1    = (float*)alloc((size_t)BT * 1024 * 4);
    unsigned short* qb    = (unsigned short*)alloc((size_t)BT * 1024 * 2);
    unsigned short* kvb   = (unsigned short*)alloc((size_t)BT * 2048 * 2);
    unsigned short* o2    = (unsigned short*)alloc((size_t)BT * 1024 * 2);
    float*          x2    = (float*)alloc((size_t)BT * 1024 * 4);
    unsigned short* mid   = (unsigned short*)alloc((size_t)BT * 4096 * 2);

    dim3 tb(32, 8);
    transpose_cast<<<dim3(3072/32, 1024/32), tb, 0, stream>>>(qkv_w, WtQKV, 1024, 3072);
    transpose_cast<<<dim3(1024/32, 1024/32), tb, 0, stream>>>(aow,   WtAO,  1024, 1024);
    transpose_cast<<<dim3(1024/32, 1024/32), tb, 0, stream>>>(q_w,   WtQ,   1024, 1024);
    transpose_cast<<<dim3(2048/32, 1024/32), tb, 0, stream>>>(kv_w,  WtKV,  1024, 2048);
    transpose_cast<<<dim3(1024/32, 1024/32), tb, 0, stream>>>(cow,   WtCO,  1024, 1024);
    transpose_cast<<<dim3(4096/32, 1024/32), tb, 0, stream>>>(f1w,   WtF1,  1024, 4096);
    transpose_cast<<<dim3(1024/32, 4096/32), tb, 0, stream>>>(f2w,   WtF2,  4096, 1024);

    cast_bf16<<<BT * 1024 / 4 / 256, 256, 0, stream>>>(ctx, ctxb);

    // self-attention block
    ln_kernel<<<BT, 256, 0, stream>>>(x, ln1_g, ln1_b, hA);
    gemm_bt<0><<<dim3(3072/128, BT/128), 256, 0, stream>>>(hA, WtQKV, qkv_b, nullptr, qkvb, BT, 3072, 1024);
    attn_kernel<<<dim3(TT/128, 64), 256, 0, stream>>>(qkvb, qkvb + 1024, qkvb + 2048, o1, 3072, 3072, 1);
    gemm_bt<2><<<dim3(1024/128, BT/128), 256, 0, stream>>>(o1, WtAO, aob, x, x1, BT, 1024, 1024);

    // cross-attention block
    ln_kernel<<<BT, 256, 0, stream>>>(x1, lnc_g, lnc_b, hA);
    gemm_bt<0><<<dim3(1024/128, BT/128), 256, 0, stream>>>(hA, WtQ, q_b, nullptr, qb, BT, 1024, 1024);
    gemm_bt<0><<<dim3(2048/128, BT/128), 256, 0, stream>>>(ctxb, WtKV, kv_b, nullptr, kvb, BT, 2048, 1024);
    attn_kernel<<<dim3(TT/128, 64), 256, 0, stream>>>(qb, kvb, kvb + 1024, o2, 1024, 2048, 0);
    gemm_bt<2><<<dim3(1024/128, BT/128), 256, 0, stream>>>(o2, WtCO, cob, x1, x2, BT, 1024, 1024);

    // FFN block
    ln_kernel<<<BT, 256, 0, stream>>>(x2, ln2_g, ln2_b, hA);
    gemm_bt<1><<<dim3(4096/128, BT/128), 256, 0, stream>>>(hA, WtF1, f1b, nullptr, mid, BT, 4096, 1024);
    gemm_bt<2><<<dim3(1024/128, BT/128), 256, 0, stream>>>(mid, WtF2, f2b, x2, (float*)d_out, BT, 1024, 4096);
}

// Round 2
// 620.182 us; speedup vs baseline: 1.1473x; 1.1473x over previous
//
#include <hip/hip_runtime.h>
#include <hip/hip_bf16.h>

#define BT 4096        // B*T rows
#define TT 1024        // T
#define HN 16          // heads

typedef __attribute__((ext_vector_type(8))) short bf16x8;
typedef __attribute__((ext_vector_type(4))) float f32x4;

__device__ __forceinline__ unsigned short f2bf(float f) {
    unsigned u = __builtin_bit_cast(unsigned, f);
    unsigned r = (u + 0x7fffu + ((u >> 16) & 1u)) >> 16;
    return (unsigned short)r;
}

__device__ __forceinline__ void g2l16(const void* g, void* l) {
    __builtin_amdgcn_global_load_lds(
        (__attribute__((address_space(1))) void*)(g),
        (__attribute__((address_space(3))) void*)(l), 16, 0, 0);
}

// ---------------------------------------------------------------- transpose+cast
// W [K x N] f32  ->  Wt [N x K] bf16
__global__ __launch_bounds__(256)
void transpose_cast(const float* __restrict__ W, unsigned short* __restrict__ Wt,
                    int K, int N)
{
    __shared__ float tile[32][33];
    int n0 = blockIdx.x * 32, k0 = blockIdx.y * 32;
    int tx = threadIdx.x, ty = threadIdx.y;
#pragma unroll
    for (int i = ty; i < 32; i += 8)
        tile[i][tx] = W[(size_t)(k0 + i) * N + n0 + tx];
    __syncthreads();
#pragma unroll
    for (int i = ty; i < 32; i += 8)
        Wt[(size_t)(n0 + i) * K + k0 + tx] = f2bf(tile[tx][i]);
}

// ---------------------------------------------------------------- V transpose (bf16)
// v slice [b][t][h*64+d] (row stride `stride`)  ->  vt [bh][d][t]
__global__ __launch_bounds__(256)
void transpose_v(const unsigned short* __restrict__ v, unsigned short* __restrict__ vt,
                 int stride)
{
    __shared__ unsigned short tile[32][33];
    int d0 = blockIdx.x * 32, t0 = blockIdx.y * 32, bh = blockIdx.z;
    int b = bh >> 4, h = bh & 15;
    int tx = threadIdx.x, ty = threadIdx.y;
#pragma unroll
    for (int i = ty; i < 32; i += 8)
        tile[i][tx] = v[((size_t)b * TT + t0 + i) * stride + h * 64 + d0 + tx];
    __syncthreads();
#pragma unroll
    for (int i = ty; i < 32; i += 8)
        vt[((size_t)bh * 64 + d0 + i) * TT + t0 + tx] = tile[tx][i];
}

// ---------------------------------------------------------------- f32 -> bf16 cast
__global__ __launch_bounds__(256)
void cast_bf16(const float* __restrict__ in, unsigned short* __restrict__ out)
{
    int i = blockIdx.x * 256 + threadIdx.x;
    float4 v = ((const float4*)in)[i];
    ushort4 o;
    o.x = f2bf(v.x); o.y = f2bf(v.y); o.z = f2bf(v.z); o.w = f2bf(v.w);
    ((ushort4*)out)[i] = o;
}

// ---------------------------------------------------------------- LayerNorm (C=1024)
__global__ __launch_bounds__(256)
void ln_kernel(const float* __restrict__ x, const float* __restrict__ g,
               const float* __restrict__ bta, unsigned short* __restrict__ out)
{
    __shared__ float red[8];
    int row = blockIdx.x;
    const float* xr = x + (size_t)row * 1024;
    float4 v = ((const float4*)xr)[threadIdx.x];
    float s = v.x + v.y + v.z + v.w;
    float q = v.x*v.x + v.y*v.y + v.z*v.z + v.w*v.w;
#pragma unroll
    for (int m = 1; m < 64; m <<= 1) {
        s += __shfl_xor(s, m, 64);
        q += __shfl_xor(q, m, 64);
    }
    int wave = threadIdx.x >> 6;
    if ((threadIdx.x & 63) == 0) { red[wave] = s; red[4 + wave] = q; }
    __syncthreads();
    s = red[0] + red[1] + red[2] + red[3];
    q = red[4] + red[5] + red[6] + red[7];
    float mean = s * (1.f / 1024.f);
    float var  = q * (1.f / 1024.f) - mean * mean;
    float rstd = rsqrtf(var + 1e-5f);
    float4 gv = ((const float4*)g)[threadIdx.x];
    float4 bv = ((const float4*)bta)[threadIdx.x];
    ushort4 o;
    o.x = f2bf((v.x - mean) * rstd * gv.x + bv.x);
    o.y = f2bf((v.y - mean) * rstd * gv.y + bv.y);
    o.z = f2bf((v.z - mean) * rstd * gv.z + bv.z);
    o.w = f2bf((v.w - mean) * rstd * gv.w + bv.w);
    ((ushort4*)(out + (size_t)row * 1024))[threadIdx.x] = o;
}

// ---------------------------------------------------------------- GEMM (m97 structure)
// C[M,N] = A[M,K](bf16) * Bt[N,K](bf16)^T + bias
// MODE 0: out bf16        MODE 1: out bf16, gelu     MODE 2: out f32, + res
template<int MODE>
__global__ __launch_bounds__(256)
void gemm_bt(const unsigned short* __restrict__ A,
             const unsigned short* __restrict__ Bt,
             const float* __restrict__ bias,
             const float* __restrict__ res,
             void* __restrict__ outp,
             int M, int N, int K)
{
    __shared__ unsigned short lA[128 * 64];
    __shared__ unsigned short lB[128 * 64];
    const int tid = threadIdx.x;
    const int wave = tid >> 6, lane = tid & 63;
    const int quad = lane >> 4, l16 = lane & 15;
    const int m0 = blockIdx.y * 128, n0 = blockIdx.x * 128;
    const int wrow = (wave >> 1) * 64, wcol = (wave & 1) * 64;

    f32x4 acc[4][4];
#pragma unroll
    for (int i = 0; i < 4; ++i)
#pragma unroll
        for (int j = 0; j < 4; ++j)
#pragma unroll
            for (int r = 0; r < 4; ++r) acc[i][j][r] = 0.f;

    for (int k0 = 0; k0 < K; k0 += 64) {
        __syncthreads();
#pragma unroll
        for (int it = 0; it < 4; ++it) {
            int chunk = it * 256 + tid;
            int row = chunk >> 3, kc = chunk & 7;
            g2l16(A  + (size_t)(m0 + row) * K + k0 + kc * 8, &lA[chunk * 8]);
            g2l16(Bt + (size_t)(n0 + row) * K + k0 + kc * 8, &lB[chunk * 8]);
        }
        __syncthreads();
#pragma unroll
        for (int kk = 0; kk < 64; kk += 32) {
            bf16x8 af[4], bfr[4];
#pragma unroll
            for (int i = 0; i < 4; ++i)
                af[i] = *(const bf16x8*)&lA[(wrow + i * 16 + l16) * 64 + kk + quad * 8];
#pragma unroll
            for (int j = 0; j < 4; ++j)
                bfr[j] = *(const bf16x8*)&lB[(wcol + j * 16 + l16) * 64 + kk + quad * 8];
#pragma unroll
            for (int i = 0; i < 4; ++i)
#pragma unroll
                for (int j = 0; j < 4; ++j)
                    acc[i][j] = __builtin_amdgcn_mfma_f32_16x16x32_bf16(af[i], bfr[j], acc[i][j], 0, 0, 0);
        }
    }

#pragma unroll
    for (int i = 0; i < 4; ++i) {
#pragma unroll
        for (int r = 0; r < 4; ++r) {
            int m = m0 + wrow + i * 16 + quad * 4 + r;
#pragma unroll
            for (int j = 0; j < 4; ++j) {
                int n = n0 + wcol + j * 16 + l16;
                float v = acc[i][j][r] + bias[n];
                if (MODE == 1) v = 0.5f * v * (1.f + erff(v * 0.70710678118654752f));
                size_t idx = (size_t)m * N + n;
                if (MODE == 2) ((float*)outp)[idx] = v + res[idx];
                else ((unsigned short*)outp)[idx] = f2bf(v);
            }
        }
    }
}

// ---------------------------------------------------------------- flash attention v2
// S^T formulation: S^T = K·Q^T so softmax is per-lane (lane owns one q column).
// grid: (T/64, B*H), 256 threads (4 waves), wave owns 16 q rows.
// lK [key][d] stride 72, lV [d][key] stride 72 (from pre-transposed vt),
// lP per-wave [q][key] stride 72. V^T comes from transpose_v kernel.
__global__ __launch_bounds__(256)
void attn_kernel(const unsigned short* __restrict__ qp,
                 const unsigned short* __restrict__ kp,
                 const unsigned short* __restrict__ vt,
                 unsigned short* __restrict__ op,
                 int qstride, int kstride, int causal)
{
    __shared__ unsigned short lK[64 * 72];
    __shared__ unsigned short lV[64 * 72];
    __shared__ unsigned short lP[4][16 * 72];

    const int tid = threadIdx.x;
    const int wave = tid >> 6, lane = tid & 63;
    const int quad = lane >> 4, l16 = lane & 15;
    const int bh = blockIdx.y, b = bh >> 4, h = bh & 15;
    const int qtile = causal ? (gridDim.x - 1 - blockIdx.x) : blockIdx.x;
    const int q0 = qtile * 64;
    const size_t rowbase = (size_t)b * TT;
    const int hoff = h * 64;
    const unsigned short* vbase = vt + (size_t)bh * 64 * TT;

    // Q as B-operand fragment: B[n=q(l16)][k=d(quad*8+j)], held in regs
    bf16x8 qf[2];
    {
        int qrow = q0 + wave * 16 + l16;
        const unsigned short* qrp = qp + (rowbase + qrow) * (size_t)qstride + hoff;
        qf[0] = *(const bf16x8*)(qrp + quad * 8);
        qf[1] = *(const bf16x8*)(qrp + 32 + quad * 8);
    }

    f32x4 oacc[4];
#pragma unroll
    for (int jd = 0; jd < 4; ++jd)
#pragma unroll
        for (int r = 0; r < 4; ++r) oacc[jd][r] = 0.f;
    float mrun = -1e30f, lrun = 0.f;

    const int nkt = causal ? (qtile + 1) : (TT / 64);
    for (int kt = 0; kt < nkt; ++kt) {
        __syncthreads();
        // stage K [key][d] and V^T [d][key] — both contiguous b128, conflict-free
#pragma unroll
        for (int it = 0; it < 2; ++it) {
            int c = it * 256 + tid;
            int r8 = c >> 3, cc = c & 7;
            *(bf16x8*)&lK[r8 * 72 + cc * 8] =
                *(const bf16x8*)(kp + (rowbase + kt * 64 + r8) * (size_t)kstride + hoff + cc * 8);
            *(bf16x8*)&lV[r8 * 72 + cc * 8] =
                *(const bf16x8*)(vbase + (size_t)r8 * TT + kt * 64 + cc * 8);
        }
        __syncthreads();

        // S^T [64 keys][16 q]: A = K rows (m=key), B = Q rows (n=q)
        f32x4 s[4];
#pragma unroll
        for (int i = 0; i < 4; ++i)
#pragma unroll
            for (int r = 0; r < 4; ++r) s[i][r] = 0.f;
#pragma unroll
        for (int kk = 0; kk < 2; ++kk) {
            bf16x8 kf[4];
#pragma unroll
            for (int i = 0; i < 4; ++i)
                kf[i] = *(const bf16x8*)&lK[(i * 16 + l16) * 72 + kk * 32 + quad * 8];
#pragma unroll
            for (int i = 0; i < 4; ++i)
                s[i] = __builtin_amdgcn_mfma_f32_16x16x32_bf16(kf[i], qf[kk], s[i], 0, 0, 0);
        }

        // softmax: lane owns q = l16; 16 key-values in regs; reduce over quad only
        const int qg = q0 + wave * 16 + l16;
        const bool domask = (causal != 0) && (kt == qtile);
        float mloc = -1e30f;
#pragma unroll
        for (int i = 0; i < 4; ++i)
#pragma unroll
            for (int r = 0; r < 4; ++r) {
                float v = s[i][r] * 0.125f;
                if (domask) {
                    int kg = kt * 64 + i * 16 + quad * 4 + r;
                    if (kg > qg) v = -1e30f;
                }
                s[i][r] = v;
                mloc = fmaxf(mloc, v);
            }
        mloc = fmaxf(mloc, __shfl_xor(mloc, 16, 64));
        mloc = fmaxf(mloc, __shfl_xor(mloc, 32, 64));
        float mn = fmaxf(mrun, mloc);
        float alpha = __expf(mrun - mn);
        mrun = mn;
        float ls = 0.f;
#pragma unroll
        for (int i = 0; i < 4; ++i)
#pragma unroll
            for (int r = 0; r < 4; ++r) {
                float p = __expf(s[i][r] - mn);
                s[i][r] = p;
                ls += p;
            }
        ls += __shfl_xor(ls, 16, 64);
        ls += __shfl_xor(ls, 32, 64);
        lrun = lrun * alpha + ls;

        // rescale O rows (row q = quad*4+r needs alpha held at lane l16 = quad*4+r)
        float arow[4];
#pragma unroll
        for (int r = 0; r < 4; ++r)
            arow[r] = __shfl(alpha, quad * 4 + r, 64);
#pragma unroll
        for (int jd = 0; jd < 4; ++jd)
#pragma unroll
            for (int r = 0; r < 4; ++r) oacc[jd][r] *= arow[r];

        // P^T -> lP[q][key]: lane writes its 16 p's as 4x ds_write_b64 (keys quad*4+r)
        unsigned short* pw = lP[wave];
#pragma unroll
        for (int i = 0; i < 4; ++i) {
            ushort4 pk;
            pk.x = f2bf(s[i][0]); pk.y = f2bf(s[i][1]);
            pk.z = f2bf(s[i][2]); pk.w = f2bf(s[i][3]);
            *(ushort4*)&pw[l16 * 72 + i * 16 + quad * 4] = pk;
        }

        // O += P V : A = P rows [q][key], B = V^T rows [d][key]
#pragma unroll
        for (int kk = 0; kk < 2; ++kk) {
            bf16x8 pf = *(const bf16x8*)&pw[l16 * 72 + kk * 32 + quad * 8];
            bf16x8 vf[4];
#pragma unroll
            for (int jd = 0; jd < 4; ++jd)
                vf[jd] = *(const bf16x8*)&lV[(jd * 16 + l16) * 72 + kk * 32 + quad * 8];
#pragma unroll
            for (int jd = 0; jd < 4; ++jd)
                oacc[jd] = __builtin_amdgcn_mfma_f32_16x16x32_bf16(pf, vf[jd], oacc[jd], 0, 0, 0);
        }
    }

    // epilogue: O rows q = quad*4+r, cols d = jd*16+l16; l for row r is at lane quad*4+r
    float ir[4];
#pragma unroll
    for (int r = 0; r < 4; ++r)
        ir[r] = 1.f / __shfl(lrun, quad * 4 + r, 64);
#pragma unroll
    for (int r = 0; r < 4; ++r) {
        int qg = q0 + wave * 16 + quad * 4 + r;
        unsigned short* orow = op + (rowbase + qg) * (size_t)1024 + hoff;
#pragma unroll
        for (int jd = 0; jd < 4; ++jd)
            orow[jd * 16 + l16] = f2bf(oacc[jd][r] * ir[r]);
    }
}

// ---------------------------------------------------------------- launch
extern "C" void kernel_launch(void* const* d_in, const int* in_sizes, int n_in,
                              void* d_out, int out_size, void* d_ws, size_t ws_size,
                              hipStream_t stream)
{
    const float* x     = (const float*)d_in[0];
    const float* ctx   = (const float*)d_in[1];
    const float* ln1_g = (const float*)d_in[2];
    const float* ln1_b = (const float*)d_in[3];
    const float* qkv_w = (const float*)d_in[4];
    const float* qkv_b = (const float*)d_in[5];
    const float* aow   = (const float*)d_in[6];
    const float* aob   = (const float*)d_in[7];
    const float* lnc_g = (const float*)d_in[8];
    const float* lnc_b = (const float*)d_in[9];
    const float* q_w   = (const float*)d_in[10];
    const float* q_b   = (const float*)d_in[11];
    const float* kv_w  = (const float*)d_in[12];
    const float* kv_b  = (const float*)d_in[13];
    const float* cow   = (const float*)d_in[14];
    const float* cob   = (const float*)d_in[15];
    const float* ln2_g = (const float*)d_in[16];
    const float* ln2_b = (const float*)d_in[17];
    const float* f1w   = (const float*)d_in[18];
    const float* f1b   = (const float*)d_in[19];
    const float* f2w   = (const float*)d_in[20];
    const float* f2b   = (const float*)d_in[21];

    char* ws = (char*)d_ws;
    size_t off = 0;
    auto alloc = [&](size_t bytes) {
        char* p = ws + off;
        off += (bytes + 255) & ~(size_t)255;
        return p;
    };

    unsigned short* WtQKV = (unsigned short*)alloc((size_t)3072 * 1024 * 2);
    unsigned short* WtAO  = (unsigned short*)alloc((size_t)1024 * 1024 * 2);
    unsigned short* WtQ   = (unsigned short*)alloc((size_t)1024 * 1024 * 2);
    unsigned short* WtKV  = (unsigned short*)alloc((size_t)2048 * 1024 * 2);
    unsigned short* WtCO  = (unsigned short*)alloc((size_t)1024 * 1024 * 2);
    unsigned short* WtF1  = (unsigned short*)alloc((size_t)4096 * 1024 * 2);
    unsigned short* WtF2  = (unsigned short*)alloc((size_t)1024 * 4096 * 2);
    unsigned short* hA    = (unsigned short*)alloc((size_t)BT * 1024 * 2);
    unsigned short* ctxb  = (unsigned short*)alloc((size_t)BT * 1024 * 2);
    unsigned short* qkvb  = (unsigned short*)alloc((size_t)BT * 3072 * 2);
    unsigned short* o1    = (unsigned short*)alloc((size_t)BT * 1024 * 2);
    float*          x1    = (float*)alloc((size_t)BT * 1024 * 4);
    unsigned short* qb    = (unsigned short*)alloc((size_t)BT * 1024 * 2);
    unsigned short* kvb   = (unsigned short*)alloc((size_t)BT * 2048 * 2);
    unsigned short* o2    = (unsigned short*)alloc((size_t)BT * 1024 * 2);
    float*          x2    = (float*)alloc((size_t)BT * 1024 * 4);
    unsigned short* mid   = (unsigned short*)alloc((size_t)BT * 4096 * 2);
    unsigned short* vT1   = (unsigned short*)alloc((size_t)BT * 1024 * 2);
    unsigned short* vT2   = (unsigned short*)alloc((size_t)BT * 1024 * 2);

    dim3 tb(32, 8);
    transpose_cast<<<dim3(3072/32, 1024/32), tb, 0, stream>>>(qkv_w, WtQKV, 1024, 3072);
    transpose_cast<<<dim3(1024/32, 1024/32), tb, 0, stream>>>(aow,   WtAO,  1024, 1024);
    transpose_cast<<<dim3(1024/32, 1024/32), tb, 0, stream>>>(q_w,   WtQ,   1024, 1024);
    transpose_cast<<<dim3(2048/32, 1024/32), tb, 0, stream>>>(kv_w,  WtKV,  1024, 2048);
    transpose_cast<<<dim3(1024/32, 1024/32), tb, 0, stream>>>(cow,   WtCO,  1024, 1024);
    transpose_cast<<<dim3(4096/32, 1024/32), tb, 0, stream>>>(f1w,   WtF1,  1024, 4096);
    transpose_cast<<<dim3(1024/32, 4096/32), tb, 0, stream>>>(f2w,   WtF2,  4096, 1024);

    cast_bf16<<<BT * 1024 / 4 / 256, 256, 0, stream>>>(ctx, ctxb);

    // self-attention block
    ln_kernel<<<BT, 256, 0, stream>>>(x, ln1_g, ln1_b, hA);
    gemm_bt<0><<<dim3(3072/128, BT/128), 256, 0, stream>>>(hA, WtQKV, qkv_b, nullptr, qkvb, BT, 3072, 1024);
    transpose_v<<<dim3(2, TT/32, 64), tb, 0, stream>>>(qkvb + 2048, vT1, 3072);
    attn_kernel<<<dim3(TT/64, 64), 256, 0, stream>>>(qkvb, qkvb + 1024, vT1, o1, 3072, 3072, 1);
    gemm_bt<2><<<dim3(1024/128, BT/128), 256, 0, stream>>>(o1, WtAO, aob, x, x1, BT, 1024, 1024);

    // cross-attention block
    ln_kernel<<<BT, 256, 0, stream>>>(x1, lnc_g, lnc_b, hA);
    gemm_bt<0><<<dim3(1024/128, BT/128), 256, 0, stream>>>(hA, WtQ, q_b, nullptr, qb, BT, 1024, 1024);
    gemm_bt<0><<<dim3(2048/128, BT/128), 256, 0, stream>>>(ctxb, WtKV, kv_b, nullptr, kvb, BT, 2048, 1024);
    transpose_v<<<dim3(2, TT/32, 64), tb, 0, stream>>>(kvb + 1024, vT2, 2048);
    attn_kernel<<<dim3(TT/64, 64), 256, 0, stream>>>(qb, kvb, vT2, o2, 1024, 2048, 0);
    gemm_bt<2><<<dim3(1024/128, BT/128), 256, 0, stream>>>(o2, WtCO, cob, x1, x2, BT, 1024, 1024);

    // FFN block
    ln_kernel<<<BT, 256, 0, stream>>>(x2, ln2_g, ln2_b, hA);
    gemm_bt<1><<<dim3(4096/128, BT/128), 256, 0, stream>>>(hA, WtF1, f1b, nullptr, mid, BT, 4096, 1024);
    gemm_bt<2><<<dim3(1024/128, BT/128), 256, 0, stream>>>(mid, WtF2, f2b, x2, (float*)d_out, BT, 1024, 4096);
}

// Round 3
// 585.879 us; speedup vs baseline: 1.2145x; 1.0585x over previous
//
#include <hip/hip_runtime.h>
#include <hip/hip_bf16.h>

#define BT 4096        // B*T rows
#define TT 1024        // T
#define HN 16          // heads

typedef __attribute__((ext_vector_type(8))) short bf16x8;
typedef __attribute__((ext_vector_type(4))) float f32x4;

__device__ __forceinline__ unsigned short f2bf(float f) {
    unsigned u = __builtin_bit_cast(unsigned, f);
    unsigned r = (u + 0x7fffu + ((u >> 16) & 1u)) >> 16;
    return (unsigned short)r;
}

__device__ __forceinline__ void g2l16(const void* g, void* l) {
    __builtin_amdgcn_global_load_lds(
        (__attribute__((address_space(1))) void*)(g),
        (__attribute__((address_space(3))) void*)(l), 16, 0, 0);
}

// ---------------------------------------------------------------- fused weight transpose
// 7 jobs: W [K x N] f32 -> Wt [N x K] bf16, flattened over blockIdx.x
struct TransJobs {
    const float* W[7];
    unsigned short* Wt[7];
    int K[7], N[7];
    int start[8];   // cumulative 32x32-tile counts
};

__global__ __launch_bounds__(256)
void transpose_all(TransJobs J)
{
    __shared__ float tile[32][33];
    int bx = blockIdx.x;
    int j = 0;
#pragma unroll
    for (int t = 0; t < 7; ++t)
        if (bx >= J.start[t + 1]) j = t + 1;
    int t = bx - J.start[j];
    int K = J.K[j], N = J.N[j];
    int ntx = N >> 5;
    int n0 = (t % ntx) * 32, k0 = (t / ntx) * 32;
    const float* W = J.W[j];
    unsigned short* Wt = J.Wt[j];
    int tx = threadIdx.x, ty = threadIdx.y;
#pragma unroll
    for (int i = ty; i < 32; i += 8)
        tile[i][tx] = W[(size_t)(k0 + i) * N + n0 + tx];
    __syncthreads();
#pragma unroll
    for (int i = ty; i < 32; i += 8)
        Wt[(size_t)(n0 + i) * K + k0 + tx] = f2bf(tile[tx][i]);
}

// ---------------------------------------------------------------- V transpose (bf16)
// v slice [b][t][h*64+d] (row stride `stride`)  ->  vt [bh][d][t]
__global__ __launch_bounds__(256)
void transpose_v(const unsigned short* __restrict__ v, unsigned short* __restrict__ vt,
                 int stride)
{
    __shared__ unsigned short tile[32][33];
    int d0 = blockIdx.x * 32, t0 = blockIdx.y * 32, bh = blockIdx.z;
    int b = bh >> 4, h = bh & 15;
    int tx = threadIdx.x, ty = threadIdx.y;
#pragma unroll
    for (int i = ty; i < 32; i += 8)
        tile[i][tx] = v[((size_t)b * TT + t0 + i) * stride + h * 64 + d0 + tx];
    __syncthreads();
#pragma unroll
    for (int i = ty; i < 32; i += 8)
        vt[((size_t)bh * 64 + d0 + i) * TT + t0 + tx] = tile[tx][i];
}

// ---------------------------------------------------------------- f32 -> bf16 cast
__global__ __launch_bounds__(256)
void cast_bf16(const float* __restrict__ in, unsigned short* __restrict__ out)
{
    int i = blockIdx.x * 256 + threadIdx.x;
    float4 v = ((const float4*)in)[i];
    ushort4 o;
    o.x = f2bf(v.x); o.y = f2bf(v.y); o.z = f2bf(v.z); o.w = f2bf(v.w);
    ((ushort4*)out)[i] = o;
}

// ---------------------------------------------------------------- LayerNorm (C=1024)
__global__ __launch_bounds__(256)
void ln_kernel(const float* __restrict__ x, const float* __restrict__ g,
               const float* __restrict__ bta, unsigned short* __restrict__ out)
{
    __shared__ float red[8];
    int row = blockIdx.x;
    const float* xr = x + (size_t)row * 1024;
    float4 v = ((const float4*)xr)[threadIdx.x];
    float s = v.x + v.y + v.z + v.w;
    float q = v.x*v.x + v.y*v.y + v.z*v.z + v.w*v.w;
#pragma unroll
    for (int m = 1; m < 64; m <<= 1) {
        s += __shfl_xor(s, m, 64);
        q += __shfl_xor(q, m, 64);
    }
    int wave = threadIdx.x >> 6;
    if ((threadIdx.x & 63) == 0) { red[wave] = s; red[4 + wave] = q; }
    __syncthreads();
    s = red[0] + red[1] + red[2] + red[3];
    q = red[4] + red[5] + red[6] + red[7];
    float mean = s * (1.f / 1024.f);
    float var  = q * (1.f / 1024.f) - mean * mean;
    float rstd = rsqrtf(var + 1e-5f);
    float4 gv = ((const float4*)g)[threadIdx.x];
    float4 bv = ((const float4*)bta)[threadIdx.x];
    ushort4 o;
    o.x = f2bf((v.x - mean) * rstd * gv.x + bv.x);
    o.y = f2bf((v.y - mean) * rstd * gv.y + bv.y);
    o.z = f2bf((v.z - mean) * rstd * gv.z + bv.z);
    o.w = f2bf((v.w - mean) * rstd * gv.w + bv.w);
    ((ushort4*)(out + (size_t)row * 1024))[threadIdx.x] = o;
}

// ---------------------------------------------------------------- GEMM core (128x128 tile)
// C[M,N] = A[M,K](bf16) * Bt[N,K](bf16)^T + bias
// MODE 0: out bf16   MODE 1: out bf16, gelu   MODE 2: out f32, + res
// MODE 3: out f32 partial (no bias), offset by caller
template<int MODE>
__device__ __forceinline__
void gemm_core(unsigned short* lA, unsigned short* lB,
               const unsigned short* __restrict__ A,
               const unsigned short* __restrict__ Bt,
               const float* __restrict__ bias,
               const float* __restrict__ res,
               void* __restrict__ outp,
               int N, int K, int m0, int n0, int kbeg, int kend)
{
    const int tid = threadIdx.x;
    const int wave = tid >> 6, lane = tid & 63;
    const int quad = lane >> 4, l16 = lane & 15;
    const int wrow = (wave >> 1) * 64, wcol = (wave & 1) * 64;

    f32x4 acc[4][4];
#pragma unroll
    for (int i = 0; i < 4; ++i)
#pragma unroll
        for (int j = 0; j < 4; ++j)
#pragma unroll
            for (int r = 0; r < 4; ++r) acc[i][j][r] = 0.f;

    for (int k0 = kbeg; k0 < kend; k0 += 64) {
        __syncthreads();
#pragma unroll
        for (int it = 0; it < 4; ++it) {
            int chunk = it * 256 + tid;
            int row = chunk >> 3, kc = chunk & 7;
            g2l16(A  + (size_t)(m0 + row) * K + k0 + kc * 8, &lA[chunk * 8]);
            g2l16(Bt + (size_t)(n0 + row) * K + k0 + kc * 8, &lB[chunk * 8]);
        }
        __syncthreads();
#pragma unroll
        for (int kk = 0; kk < 64; kk += 32) {
            bf16x8 af[4], bfr[4];
#pragma unroll
            for (int i = 0; i < 4; ++i)
                af[i] = *(const bf16x8*)&lA[(wrow + i * 16 + l16) * 64 + kk + quad * 8];
#pragma unroll
            for (int j = 0; j < 4; ++j)
                bfr[j] = *(const bf16x8*)&lB[(wcol + j * 16 + l16) * 64 + kk + quad * 8];
#pragma unroll
            for (int i = 0; i < 4; ++i)
#pragma unroll
                for (int j = 0; j < 4; ++j)
                    acc[i][j] = __builtin_amdgcn_mfma_f32_16x16x32_bf16(af[i], bfr[j], acc[i][j], 0, 0, 0);
        }
    }

#pragma unroll
    for (int i = 0; i < 4; ++i) {
#pragma unroll
        for (int r = 0; r < 4; ++r) {
            int m = m0 + wrow + i * 16 + quad * 4 + r;
#pragma unroll
            for (int j = 0; j < 4; ++j) {
                int n = n0 + wcol + j * 16 + l16;
                float v = acc[i][j][r];
                if (MODE != 3) v += bias[n];
                if (MODE == 1) v = 0.5f * v * (1.f + erff(v * 0.70710678118654752f));
                size_t idx = (size_t)m * N + n;
                if (MODE == 2) ((float*)outp)[idx] = v + res[idx];
                else if (MODE == 3) ((float*)outp)[idx] = v;
                else ((unsigned short*)outp)[idx] = f2bf(v);
            }
        }
    }
}

template<int MODE>
__global__ __launch_bounds__(256)
void gemm_bt(const unsigned short* __restrict__ A,
             const unsigned short* __restrict__ Bt,
             const float* __restrict__ bias,
             const float* __restrict__ res,
             void* __restrict__ outp,
             int M, int N, int K)
{
    __shared__ unsigned short lA[128 * 64];
    __shared__ unsigned short lB[128 * 64];
    gemm_core<MODE>(lA, lB, A, Bt, bias, res, outp, N, K,
                    blockIdx.y * 128, blockIdx.x * 128, 0, K);
}

// fused q + kv GEMM: both M=4096, K=1024, bf16-out
__global__ __launch_bounds__(256)
void gemm_dual(const unsigned short* __restrict__ A1, const unsigned short* __restrict__ B1,
               const float* __restrict__ b1, unsigned short* __restrict__ o1p, int N1, int nbx1,
               const unsigned short* __restrict__ A2, const unsigned short* __restrict__ B2,
               const float* __restrict__ b2, unsigned short* __restrict__ o2p, int N2,
               int K)
{
    __shared__ unsigned short lA[128 * 64];
    __shared__ unsigned short lB[128 * 64];
    int bx = blockIdx.x;
    if (bx < nbx1)
        gemm_core<0>(lA, lB, A1, B1, b1, nullptr, o1p, N1, K,
                     blockIdx.y * 128, bx * 128, 0, K);
    else
        gemm_core<0>(lA, lB, A2, B2, b2, nullptr, o2p, N2, K,
                     blockIdx.y * 128, (bx - nbx1) * 128, 0, K);
}

// split-K GEMM: grid.z = S slices, fp32 partials, no bias
__global__ __launch_bounds__(256)
void gemm_splitk(const unsigned short* __restrict__ A,
                 const unsigned short* __restrict__ Bt,
                 float* __restrict__ part,
                 int M, int N, int K, int kslice)
{
    __shared__ unsigned short lA[128 * 64];
    __shared__ unsigned short lB[128 * 64];
    int kz = blockIdx.z;
    gemm_core<3>(lA, lB, A, Bt, nullptr, nullptr,
                 part + (size_t)kz * M * N, N, K,
                 blockIdx.y * 128, blockIdx.x * 128,
                 kz * kslice, (kz + 1) * kslice);
}

// reduce 4 partials + bias + res -> f32 out
__global__ __launch_bounds__(256)
void reduce4(const float* __restrict__ part, const float* __restrict__ bias,
             const float* __restrict__ res, float* __restrict__ out, int MN)
{
    int i = blockIdx.x * 256 + threadIdx.x;
    const float4* p = (const float4*)part;
    int q = MN >> 2;
    float4 a = p[i], b = p[i + q], c = p[i + 2 * q], d = p[i + 3 * q];
    float4 bs = ((const float4*)bias)[i & 255];
    float4 rr = ((const float4*)res)[i];
    float4 o;
    o.x = a.x + b.x + c.x + d.x + bs.x + rr.x;
    o.y = a.y + b.y + c.y + d.y + bs.y + rr.y;
    o.z = a.z + b.z + c.z + d.z + bs.z + rr.z;
    o.w = a.w + b.w + c.w + d.w + bs.w + rr.w;
    ((float4*)out)[i] = o;
}

// ---------------------------------------------------------------- small GEMM (64x128 tile)
// for N=1024, M=4096 GEMMs: grid (N/128, M/64) = 512 blocks. MODE 2 epilogue.
__global__ __launch_bounds__(256)
void gemm_small2(const unsigned short* __restrict__ A,
                 const unsigned short* __restrict__ Bt,
                 const float* __restrict__ bias,
                 const float* __restrict__ res,
                 float* __restrict__ outp,
                 int M, int N, int K)
{
    __shared__ unsigned short lA[64 * 64];
    __shared__ unsigned short lB[128 * 64];
    const int tid = threadIdx.x;
    const int wave = tid >> 6, lane = tid & 63;
    const int quad = lane >> 4, l16 = lane & 15;
    const int m0 = blockIdx.y * 64, n0 = blockIdx.x * 128;
    const int wrow = (wave >> 1) * 32, wcol = (wave & 1) * 64;

    f32x4 acc[2][4];
#pragma unroll
    for (int i = 0; i < 2; ++i)
#pragma unroll
        for (int j = 0; j < 4; ++j)
#pragma unroll
            for (int r = 0; r < 4; ++r) acc[i][j][r] = 0.f;

    for (int k0 = 0; k0 < K; k0 += 64) {
        __syncthreads();
#pragma unroll
        for (int it = 0; it < 6; ++it) {
            int chunk = it * 256 + tid;
            if (chunk < 512) {
                int row = chunk >> 3, kc = chunk & 7;
                g2l16(A + (size_t)(m0 + row) * K + k0 + kc * 8, &lA[chunk * 8]);
            } else {
                int cb = chunk - 512;
                int row = cb >> 3, kc = cb & 7;
                g2l16(Bt + (size_t)(n0 + row) * K + k0 + kc * 8, &lB[cb * 8]);
            }
        }
        __syncthreads();
#pragma unroll
        for (int kk = 0; kk < 64; kk += 32) {
            bf16x8 af[2], bfr[4];
#pragma unroll
            for (int i = 0; i < 2; ++i)
                af[i] = *(const bf16x8*)&lA[(wrow + i * 16 + l16) * 64 + kk + quad * 8];
#pragma unroll
            for (int j = 0; j < 4; ++j)
                bfr[j] = *(const bf16x8*)&lB[(wcol + j * 16 + l16) * 64 + kk + quad * 8];
#pragma unroll
            for (int i = 0; i < 2; ++i)
#pragma unroll
                for (int j = 0; j < 4; ++j)
                    acc[i][j] = __builtin_amdgcn_mfma_f32_16x16x32_bf16(af[i], bfr[j], acc[i][j], 0, 0, 0);
        }
    }

#pragma unroll
    for (int i = 0; i < 2; ++i) {
#pragma unroll
        for (int r = 0; r < 4; ++r) {
            int m = m0 + wrow + i * 16 + quad * 4 + r;
#pragma unroll
            for (int j = 0; j < 4; ++j) {
                int n = n0 + wcol + j * 16 + l16;
                size_t idx = (size_t)m * N + n;
                outp[idx] = acc[i][j][r] + bias[n] + res[idx];
            }
        }
    }
}

// ---------------------------------------------------------------- flash attention v2
__global__ __launch_bounds__(256)
void attn_kernel(const unsigned short* __restrict__ qp,
                 const unsigned short* __restrict__ kp,
                 const unsigned short* __restrict__ vt,
                 unsigned short* __restrict__ op,
                 int qstride, int kstride, int causal)
{
    __shared__ unsigned short lK[64 * 72];
    __shared__ unsigned short lV[64 * 72];
    __shared__ unsigned short lP[4][16 * 72];

    const int tid = threadIdx.x;
    const int wave = tid >> 6, lane = tid & 63;
    const int quad = lane >> 4, l16 = lane & 15;
    const int bh = blockIdx.y, b = bh >> 4, h = bh & 15;
    const int qtile = causal ? (gridDim.x - 1 - blockIdx.x) : blockIdx.x;
    const int q0 = qtile * 64;
    const size_t rowbase = (size_t)b * TT;
    const int hoff = h * 64;
    const unsigned short* vbase = vt + (size_t)bh * 64 * TT;

    bf16x8 qf[2];
    {
        int qrow = q0 + wave * 16 + l16;
        const unsigned short* qrp = qp + (rowbase + qrow) * (size_t)qstride + hoff;
        qf[0] = *(const bf16x8*)(qrp + quad * 8);
        qf[1] = *(const bf16x8*)(qrp + 32 + quad * 8);
    }

    f32x4 oacc[4];
#pragma unroll
    for (int jd = 0; jd < 4; ++jd)
#pragma unroll
        for (int r = 0; r < 4; ++r) oacc[jd][r] = 0.f;
    float mrun = -1e30f, lrun = 0.f;

    const int nkt = causal ? (qtile + 1) : (TT / 64);
    for (int kt = 0; kt < nkt; ++kt) {
        __syncthreads();
#pragma unroll
        for (int it = 0; it < 2; ++it) {
            int c = it * 256 + tid;
            int r8 = c >> 3, cc = c & 7;
            *(bf16x8*)&lK[r8 * 72 + cc * 8] =
                *(const bf16x8*)(kp + (rowbase + kt * 64 + r8) * (size_t)kstride + hoff + cc * 8);
            *(bf16x8*)&lV[r8 * 72 + cc * 8] =
                *(const bf16x8*)(vbase + (size_t)r8 * TT + kt * 64 + cc * 8);
        }
        __syncthreads();

        f32x4 s[4];
#pragma unroll
        for (int i = 0; i < 4; ++i)
#pragma unroll
            for (int r = 0; r < 4; ++r) s[i][r] = 0.f;
#pragma unroll
        for (int kk = 0; kk < 2; ++kk) {
            bf16x8 kf[4];
#pragma unroll
            for (int i = 0; i < 4; ++i)
                kf[i] = *(const bf16x8*)&lK[(i * 16 + l16) * 72 + kk * 32 + quad * 8];
#pragma unroll
            for (int i = 0; i < 4; ++i)
                s[i] = __builtin_amdgcn_mfma_f32_16x16x32_bf16(kf[i], qf[kk], s[i], 0, 0, 0);
        }

        const int qg = q0 + wave * 16 + l16;
        const bool domask = (causal != 0) && (kt == qtile);
        float mloc = -1e30f;
#pragma unroll
        for (int i = 0; i < 4; ++i)
#pragma unroll
            for (int r = 0; r < 4; ++r) {
                float v = s[i][r] * 0.125f;
                if (domask) {
                    int kg = kt * 64 + i * 16 + quad * 4 + r;
                    if (kg > qg) v = -1e30f;
                }
                s[i][r] = v;
                mloc = fmaxf(mloc, v);
            }
        mloc = fmaxf(mloc, __shfl_xor(mloc, 16, 64));
        mloc = fmaxf(mloc, __shfl_xor(mloc, 32, 64));
        float mn = fmaxf(mrun, mloc);
        float alpha = __expf(mrun - mn);
        mrun = mn;
        float ls = 0.f;
#pragma unroll
        for (int i = 0; i < 4; ++i)
#pragma unroll
            for (int r = 0; r < 4; ++r) {
                float p = __expf(s[i][r] - mn);
                s[i][r] = p;
                ls += p;
            }
        ls += __shfl_xor(ls, 16, 64);
        ls += __shfl_xor(ls, 32, 64);
        lrun = lrun * alpha + ls;

        float arow[4];
#pragma unroll
        for (int r = 0; r < 4; ++r)
            arow[r] = __shfl(alpha, quad * 4 + r, 64);
#pragma unroll
        for (int jd = 0; jd < 4; ++jd)
#pragma unroll
            for (int r = 0; r < 4; ++r) oacc[jd][r] *= arow[r];

        unsigned short* pw = lP[wave];
#pragma unroll
        for (int i = 0; i < 4; ++i) {
            ushort4 pk;
            pk.x = f2bf(s[i][0]); pk.y = f2bf(s[i][1]);
            pk.z = f2bf(s[i][2]); pk.w = f2bf(s[i][3]);
            *(ushort4*)&pw[l16 * 72 + i * 16 + quad * 4] = pk;
        }

#pragma unroll
        for (int kk = 0; kk < 2; ++kk) {
            bf16x8 pf = *(const bf16x8*)&pw[l16 * 72 + kk * 32 + quad * 8];
            bf16x8 vf[4];
#pragma unroll
            for (int jd = 0; jd < 4; ++jd)
                vf[jd] = *(const bf16x8*)&lV[(jd * 16 + l16) * 72 + kk * 32 + quad * 8];
#pragma unroll
            for (int jd = 0; jd < 4; ++jd)
                oacc[jd] = __builtin_amdgcn_mfma_f32_16x16x32_bf16(pf, vf[jd], oacc[jd], 0, 0, 0);
        }
    }

    float ir[4];
#pragma unroll
    for (int r = 0; r < 4; ++r)
        ir[r] = 1.f / __shfl(lrun, quad * 4 + r, 64);
#pragma unroll
    for (int r = 0; r < 4; ++r) {
        int qg = q0 + wave * 16 + quad * 4 + r;
        unsigned short* orow = op + (rowbase + qg) * (size_t)1024 + hoff;
#pragma unroll
        for (int jd = 0; jd < 4; ++jd)
            orow[jd * 16 + l16] = f2bf(oacc[jd][r] * ir[r]);
    }
}

// ---------------------------------------------------------------- launch
extern "C" void kernel_launch(void* const* d_in, const int* in_sizes, int n_in,
                              void* d_out, int out_size, void* d_ws, size_t ws_size,
                              hipStream_t stream)
{
    const float* x     = (const float*)d_in[0];
    const float* ctx   = (const float*)d_in[1];
    const float* ln1_g = (const float*)d_in[2];
    const float* ln1_b = (const float*)d_in[3];
    const float* qkv_w = (const float*)d_in[4];
    const float* qkv_b = (const float*)d_in[5];
    const float* aow   = (const float*)d_in[6];
    const float* aob   = (const float*)d_in[7];
    const float* lnc_g = (const float*)d_in[8];
    const float* lnc_b = (const float*)d_in[9];
    const float* q_w   = (const float*)d_in[10];
    const float* q_b   = (const float*)d_in[11];
    const float* kv_w  = (const float*)d_in[12];
    const float* kv_b  = (const float*)d_in[13];
    const float* cow   = (const float*)d_in[14];
    const float* cob   = (const float*)d_in[15];
    const float* ln2_g = (const float*)d_in[16];
    const float* ln2_b = (const float*)d_in[17];
    const float* f1w   = (const float*)d_in[18];
    const float* f1b   = (const float*)d_in[19];
    const float* f2w   = (const float*)d_in[20];
    const float* f2b   = (const float*)d_in[21];

    char* ws = (char*)d_ws;
    size_t off = 0;
    auto alloc = [&](size_t bytes) {
        char* p = ws + off;
        off += (bytes + 255) & ~(size_t)255;
        return p;
    };

    unsigned short* WtQKV = (unsigned short*)alloc((size_t)3072 * 1024 * 2);
    unsigned short* WtAO  = (unsigned short*)alloc((size_t)1024 * 1024 * 2);
    unsigned short* WtQ   = (unsigned short*)alloc((size_t)1024 * 1024 * 2);
    unsigned short* WtKV  = (unsigned short*)alloc((size_t)2048 * 1024 * 2);
    unsigned short* WtCO  = (unsigned short*)alloc((size_t)1024 * 1024 * 2);
    unsigned short* WtF1  = (unsigned short*)alloc((size_t)4096 * 1024 * 2);
    unsigned short* WtF2  = (unsigned short*)alloc((size_t)1024 * 4096 * 2);
    unsigned short* hA    = (unsigned short*)alloc((size_t)BT * 1024 * 2);
    unsigned short* ctxb  = (unsigned short*)alloc((size_t)BT * 1024 * 2);
    unsigned short* qkvb  = (unsigned short*)alloc((size_t)BT * 3072 * 2);
    unsigned short* o1    = (unsigned short*)alloc((size_t)BT * 1024 * 2);
    float*          x1    = (float*)alloc((size_t)BT * 1024 * 4);
    unsigned short* qb    = (unsigned short*)alloc((size_t)BT * 1024 * 2);
    unsigned short* kvb   = (unsigned short*)alloc((size_t)BT * 2048 * 2);
    unsigned short* o2    = (unsigned short*)alloc((size_t)BT * 1024 * 2);
    float*          x2    = (float*)alloc((size_t)BT * 1024 * 4);
    unsigned short* mid   = (unsigned short*)alloc((size_t)BT * 4096 * 2);
    unsigned short* vT1   = (unsigned short*)alloc((size_t)BT * 1024 * 2);
    unsigned short* vT2   = (unsigned short*)alloc((size_t)BT * 1024 * 2);

    // split-K partials (4 x 4096 x 1024 f32 = 67 MB) reuse the dead
    // qkvb..o2 region (75.5 MB), all consumed before FFN2 runs.
    float* partials = (float*)qkvb;

    // fused weight transposes: 7 jobs
    TransJobs J;
    J.W[0]=qkv_w; J.Wt[0]=WtQKV; J.K[0]=1024; J.N[0]=3072;
    J.W[1]=aow;   J.Wt[1]=WtAO;  J.K[1]=1024; J.N[1]=1024;
    J.W[2]=q_w;   J.Wt[2]=WtQ;   J.K[2]=1024; J.N[2]=1024;
    J.W[3]=kv_w;  J.Wt[3]=WtKV;  J.K[3]=1024; J.N[3]=2048;
    J.W[4]=cow;   J.Wt[4]=WtCO;  J.K[4]=1024; J.N[4]=1024;
    J.W[5]=f1w;   J.Wt[5]=WtF1;  J.K[5]=1024; J.N[5]=4096;
    J.W[6]=f2w;   J.Wt[6]=WtF2;  J.K[6]=4096; J.N[6]=1024;
    int acc = 0;
    for (int j = 0; j < 7; ++j) {
        J.start[j] = acc;
        acc += (J.N[j] / 32) * (J.K[j] / 32);
    }
    J.start[7] = acc;

    dim3 tb(32, 8);
    transpose_all<<<acc, tb, 0, stream>>>(J);
    cast_bf16<<<BT * 1024 / 4 / 256, 256, 0, stream>>>(ctx, ctxb);

    // self-attention block
    ln_kernel<<<BT, 256, 0, stream>>>(x, ln1_g, ln1_b, hA);
    gemm_bt<0><<<dim3(3072/128, BT/128), 256, 0, stream>>>(hA, WtQKV, qkv_b, nullptr, qkvb, BT, 3072, 1024);
    transpose_v<<<dim3(2, TT/32, 64), tb, 0, stream>>>(qkvb + 2048, vT1, 3072);
    attn_kernel<<<dim3(TT/64, 64), 256, 0, stream>>>(qkvb, qkvb + 1024, vT1, o1, 3072, 3072, 1);
    gemm_small2<<<dim3(1024/128, BT/64), 256, 0, stream>>>(o1, WtAO, aob, x, x1, BT, 1024, 1024);

    // cross-attention block: q-GEMM and kv-GEMM fused into one launch
    ln_kernel<<<BT, 256, 0, stream>>>(x1, lnc_g, lnc_b, hA);
    gemm_dual<<<dim3(1024/128 + 2048/128, BT/128), 256, 0, stream>>>(
        hA, WtQ, q_b, qb, 1024, 1024/128,
        ctxb, WtKV, kv_b, kvb, 2048, 1024);
    transpose_v<<<dim3(2, TT/32, 64), tb, 0, stream>>>(kvb + 1024, vT2, 2048);
    attn_kernel<<<dim3(TT/64, 64), 256, 0, stream>>>(qb, kvb, vT2, o2, 1024, 2048, 0);
    gemm_small2<<<dim3(1024/128, BT/64), 256, 0, stream>>>(o2, WtCO, cob, x1, x2, BT, 1024, 1024);

    // FFN block
    ln_kernel<<<BT, 256, 0, stream>>>(x2, ln2_g, ln2_b, hA);
    gemm_bt<1><<<dim3(4096/128, BT/128), 256, 0, stream>>>(hA, WtF1, f1b, nullptr, mid, BT, 4096, 1024);
    gemm_splitk<<<dim3(1024/128, BT/128, 4), 256, 0, stream>>>(mid, WtF2, partials, BT, 1024, 4096, 1024);
    reduce4<<<BT * 1024 / 4 / 256, 256, 0, stream>>>(partials, f2b, x2, (float*)d_out, BT * 1024);
}

// Round 4
// 541.111 us; speedup vs baseline: 1.3150x; 1.0827x over previous
//
#include <hip/hip_runtime.h>
#include <hip/hip_bf16.h>

#define BT 4096        // B*T rows
#define TT 1024        // T
#define HN 16          // heads

typedef __attribute__((ext_vector_type(8))) short bf16x8;
typedef __attribute__((ext_vector_type(4))) float f32x4;

__device__ __forceinline__ unsigned short f2bf(float f) {
    unsigned u = __builtin_bit_cast(unsigned, f);
    unsigned r = (u + 0x7fffu + ((u >> 16) & 1u)) >> 16;
    return (unsigned short)r;
}

__device__ __forceinline__ void g2l16(const void* g, void* l) {
    __builtin_amdgcn_global_load_lds(
        (__attribute__((address_space(1))) void*)(g),
        (__attribute__((address_space(3))) void*)(l), 16, 0, 0);
}

// tanh-approx gelu via hardware exp; overflow-safe
__device__ __forceinline__ float gelu_f(float v) {
    float t = v * (0.7978845608f + 0.0356774081f * v * v);
    float e = __expf(2.f * t);
    float th = 1.f - 2.f / (e + 1.f);
    return 0.5f * v * (1.f + th);
}

// ---------------------------------------------------------------- fused weight transpose
struct TransJobs {
    const float* W[7];
    unsigned short* Wt[7];
    int K[7], N[7];
    int start[8];
};

__global__ __launch_bounds__(256)
void transpose_all(TransJobs J)
{
    __shared__ float tile[32][33];
    int bx = blockIdx.x;
    int j = 0;
#pragma unroll
    for (int t = 0; t < 7; ++t)
        if (bx >= J.start[t + 1]) j = t + 1;
    int t = bx - J.start[j];
    int K = J.K[j], N = J.N[j];
    int ntx = N >> 5;
    int n0 = (t % ntx) * 32, k0 = (t / ntx) * 32;
    const float* W = J.W[j];
    unsigned short* Wt = J.Wt[j];
    int tx = threadIdx.x, ty = threadIdx.y;
#pragma unroll
    for (int i = ty; i < 32; i += 8)
        tile[i][tx] = W[(size_t)(k0 + i) * N + n0 + tx];
    __syncthreads();
#pragma unroll
    for (int i = ty; i < 32; i += 8)
        Wt[(size_t)(n0 + i) * K + k0 + tx] = f2bf(tile[tx][i]);
}

// ---------------------------------------------------------------- V transpose (bf16)
__global__ __launch_bounds__(256)
void transpose_v(const unsigned short* __restrict__ v, unsigned short* __restrict__ vt,
                 int stride)
{
    __shared__ unsigned short tile[32][33];
    int d0 = blockIdx.x * 32, t0 = blockIdx.y * 32, bh = blockIdx.z;
    int b = bh >> 4, h = bh & 15;
    int tx = threadIdx.x, ty = threadIdx.y;
#pragma unroll
    for (int i = ty; i < 32; i += 8)
        tile[i][tx] = v[((size_t)b * TT + t0 + i) * stride + h * 64 + d0 + tx];
    __syncthreads();
#pragma unroll
    for (int i = ty; i < 32; i += 8)
        vt[((size_t)bh * 64 + d0 + i) * TT + t0 + tx] = tile[tx][i];
}

// ---------------------------------------------------------------- f32 -> bf16 cast
__global__ __launch_bounds__(256)
void cast_bf16(const float* __restrict__ in, unsigned short* __restrict__ out)
{
    int i = blockIdx.x * 256 + threadIdx.x;
    float4 v = ((const float4*)in)[i];
    ushort4 o;
    o.x = f2bf(v.x); o.y = f2bf(v.y); o.z = f2bf(v.z); o.w = f2bf(v.w);
    ((ushort4*)out)[i] = o;
}

// ---------------------------------------------------------------- LayerNorm (C=1024)
__global__ __launch_bounds__(256)
void ln_kernel(const float* __restrict__ x, const float* __restrict__ g,
               const float* __restrict__ bta, unsigned short* __restrict__ out)
{
    __shared__ float red[8];
    int row = blockIdx.x;
    const float* xr = x + (size_t)row * 1024;
    float4 v = ((const float4*)xr)[threadIdx.x];
    float s = v.x + v.y + v.z + v.w;
    float q = v.x*v.x + v.y*v.y + v.z*v.z + v.w*v.w;
#pragma unroll
    for (int m = 1; m < 64; m <<= 1) {
        s += __shfl_xor(s, m, 64);
        q += __shfl_xor(q, m, 64);
    }
    int wave = threadIdx.x >> 6;
    if ((threadIdx.x & 63) == 0) { red[wave] = s; red[4 + wave] = q; }
    __syncthreads();
    s = red[0] + red[1] + red[2] + red[3];
    q = red[4] + red[5] + red[6] + red[7];
    float mean = s * (1.f / 1024.f);
    float var  = q * (1.f / 1024.f) - mean * mean;
    float rstd = rsqrtf(var + 1e-5f);
    float4 gv = ((const float4*)g)[threadIdx.x];
    float4 bv = ((const float4*)bta)[threadIdx.x];
    ushort4 o;
    o.x = f2bf((v.x - mean) * rstd * gv.x + bv.x);
    o.y = f2bf((v.y - mean) * rstd * gv.y + bv.y);
    o.z = f2bf((v.z - mean) * rstd * gv.z + bv.z);
    o.w = f2bf((v.w - mean) * rstd * gv.w + bv.w);
    ((ushort4*)(out + (size_t)row * 1024))[threadIdx.x] = o;
}

// ---------------------------------------------------------------- GEMM core (128x128 tile)
// XOR-swizzled LDS: global chunk kc lives at slot kc^(row&7); row stride 64 elem.
// MODE 0: out bf16   MODE 1: out bf16, gelu   MODE 2: out f32, + res
// MODE 3: out f32 partial (no bias)
template<int MODE>
__device__ __forceinline__
void gemm_core(unsigned short* lA, unsigned short* lB,
               const unsigned short* __restrict__ A,
               const unsigned short* __restrict__ Bt,
               const float* __restrict__ bias,
               const float* __restrict__ res,
               void* __restrict__ outp,
               int N, int K, int m0, int n0, int kbeg, int kend)
{
    const int tid = threadIdx.x;
    const int wave = tid >> 6, lane = tid & 63;
    const int quad = lane >> 4, l16 = lane & 15;
    const int sw = l16 & 7;
    const int wrow = (wave >> 1) * 64, wcol = (wave & 1) * 64;

    f32x4 acc[4][4];
#pragma unroll
    for (int i = 0; i < 4; ++i)
#pragma unroll
        for (int j = 0; j < 4; ++j)
#pragma unroll
            for (int r = 0; r < 4; ++r) acc[i][j][r] = 0.f;

    for (int k0 = kbeg; k0 < kend; k0 += 64) {
        __syncthreads();
#pragma unroll
        for (int it = 0; it < 4; ++it) {
            int chunk = it * 256 + tid;
            int row = chunk >> 3, slot = chunk & 7;
            int kc = slot ^ (row & 7);                 // swizzled source chunk
            g2l16(A  + (size_t)(m0 + row) * K + k0 + kc * 8, &lA[chunk * 8]);
            g2l16(Bt + (size_t)(n0 + row) * K + k0 + kc * 8, &lB[chunk * 8]);
        }
        __syncthreads();
#pragma unroll
        for (int kk = 0; kk < 64; kk += 32) {
            const int gc = (kk >> 3) + quad;           // global chunk 0..7
            const int sl = (gc ^ sw) * 8;              // swizzled slot (elems)
            bf16x8 af[4], bfr[4];
#pragma unroll
            for (int i = 0; i < 4; ++i)
                af[i] = *(const bf16x8*)&lA[(wrow + i * 16 + l16) * 64 + sl];
#pragma unroll
            for (int j = 0; j < 4; ++j)
                bfr[j] = *(const bf16x8*)&lB[(wcol + j * 16 + l16) * 64 + sl];
#pragma unroll
            for (int i = 0; i < 4; ++i)
#pragma unroll
                for (int j = 0; j < 4; ++j)
                    acc[i][j] = __builtin_amdgcn_mfma_f32_16x16x32_bf16(af[i], bfr[j], acc[i][j], 0, 0, 0);
        }
    }

#pragma unroll
    for (int i = 0; i < 4; ++i) {
#pragma unroll
        for (int r = 0; r < 4; ++r) {
            int m = m0 + wrow + i * 16 + quad * 4 + r;
#pragma unroll
            for (int j = 0; j < 4; ++j) {
                int n = n0 + wcol + j * 16 + l16;
                float v = acc[i][j][r];
                if (MODE != 3) v += bias[n];
                if (MODE == 1) v = gelu_f(v);
                size_t idx = (size_t)m * N + n;
                if (MODE == 2) ((float*)outp)[idx] = v + res[idx];
                else if (MODE == 3) ((float*)outp)[idx] = v;
                else ((unsigned short*)outp)[idx] = f2bf(v);
            }
        }
    }
}

template<int MODE>
__global__ __launch_bounds__(256)
void gemm_bt(const unsigned short* __restrict__ A,
             const unsigned short* __restrict__ Bt,
             const float* __restrict__ bias,
             const float* __restrict__ res,
             void* __restrict__ outp,
             int M, int N, int K)
{
    __shared__ unsigned short lA[128 * 64];
    __shared__ unsigned short lB[128 * 64];
    gemm_core<MODE>(lA, lB, A, Bt, bias, res, outp, N, K,
                    blockIdx.y * 128, blockIdx.x * 128, 0, K);
}

// fused q + kv GEMM
__global__ __launch_bounds__(256)
void gemm_dual(const unsigned short* __restrict__ A1, const unsigned short* __restrict__ B1,
               const float* __restrict__ b1, unsigned short* __restrict__ o1p, int N1, int nbx1,
               const unsigned short* __restrict__ A2, const unsigned short* __restrict__ B2,
               const float* __restrict__ b2, unsigned short* __restrict__ o2p, int N2,
               int K)
{
    __shared__ unsigned short lA[128 * 64];
    __shared__ unsigned short lB[128 * 64];
    int bx = blockIdx.x;
    if (bx < nbx1)
        gemm_core<0>(lA, lB, A1, B1, b1, nullptr, o1p, N1, K,
                     blockIdx.y * 128, bx * 128, 0, K);
    else
        gemm_core<0>(lA, lB, A2, B2, b2, nullptr, o2p, N2, K,
                     blockIdx.y * 128, (bx - nbx1) * 128, 0, K);
}

// split-K GEMM
__global__ __launch_bounds__(256)
void gemm_splitk(const unsigned short* __restrict__ A,
                 const unsigned short* __restrict__ Bt,
                 float* __restrict__ part,
                 int M, int N, int K, int kslice)
{
    __shared__ unsigned short lA[128 * 64];
    __shared__ unsigned short lB[128 * 64];
    int kz = blockIdx.z;
    gemm_core<3>(lA, lB, A, Bt, nullptr, nullptr,
                 part + (size_t)kz * M * N, N, K,
                 blockIdx.y * 128, blockIdx.x * 128,
                 kz * kslice, (kz + 1) * kslice);
}

// reduce 4 partials + bias + res -> f32 out
__global__ __launch_bounds__(256)
void reduce4(const float* __restrict__ part, const float* __restrict__ bias,
             const float* __restrict__ res, float* __restrict__ out, int MN)
{
    int i = blockIdx.x * 256 + threadIdx.x;
    const float4* p = (const float4*)part;
    int q = MN >> 2;
    float4 a = p[i], b = p[i + q], c = p[i + 2 * q], d = p[i + 3 * q];
    float4 bs = ((const float4*)bias)[i & 255];
    float4 rr = ((const float4*)res)[i];
    float4 o;
    o.x = a.x + b.x + c.x + d.x + bs.x + rr.x;
    o.y = a.y + b.y + c.y + d.y + bs.y + rr.y;
    o.z = a.z + b.z + c.z + d.z + bs.z + rr.z;
    o.w = a.w + b.w + c.w + d.w + bs.w + rr.w;
    ((float4*)out)[i] = o;
}

// ---------------------------------------------------------------- small GEMM (64x128 tile)
__global__ __launch_bounds__(256)
void gemm_small2(const unsigned short* __restrict__ A,
                 const unsigned short* __restrict__ Bt,
                 const float* __restrict__ bias,
                 const float* __restrict__ res,
                 float* __restrict__ outp,
                 int M, int N, int K)
{
    __shared__ unsigned short lA[64 * 64];
    __shared__ unsigned short lB[128 * 64];
    const int tid = threadIdx.x;
    const int wave = tid >> 6, lane = tid & 63;
    const int quad = lane >> 4, l16 = lane & 15;
    const int sw = l16 & 7;
    const int m0 = blockIdx.y * 64, n0 = blockIdx.x * 128;
    const int wrow = (wave >> 1) * 32, wcol = (wave & 1) * 64;

    f32x4 acc[2][4];
#pragma unroll
    for (int i = 0; i < 2; ++i)
#pragma unroll
        for (int j = 0; j < 4; ++j)
#pragma unroll
            for (int r = 0; r < 4; ++r) acc[i][j][r] = 0.f;

    for (int k0 = 0; k0 < K; k0 += 64) {
        __syncthreads();
#pragma unroll
        for (int it = 0; it < 6; ++it) {
            int chunk = it * 256 + tid;
            if (chunk < 512) {
                int row = chunk >> 3, slot = chunk & 7;
                int kc = slot ^ (row & 7);
                g2l16(A + (size_t)(m0 + row) * K + k0 + kc * 8, &lA[chunk * 8]);
            } else {
                int cb = chunk - 512;
                int row = cb >> 3, slot = cb & 7;
                int kc = slot ^ (row & 7);
                g2l16(Bt + (size_t)(n0 + row) * K + k0 + kc * 8, &lB[cb * 8]);
            }
        }
        __syncthreads();
#pragma unroll
        for (int kk = 0; kk < 64; kk += 32) {
            const int gc = (kk >> 3) + quad;
            const int sl = (gc ^ sw) * 8;
            bf16x8 af[2], bfr[4];
#pragma unroll
            for (int i = 0; i < 2; ++i)
                af[i] = *(const bf16x8*)&lA[(wrow + i * 16 + l16) * 64 + sl];
#pragma unroll
            for (int j = 0; j < 4; ++j)
                bfr[j] = *(const bf16x8*)&lB[(wcol + j * 16 + l16) * 64 + sl];
#pragma unroll
            for (int i = 0; i < 2; ++i)
#pragma unroll
                for (int j = 0; j < 4; ++j)
                    acc[i][j] = __builtin_amdgcn_mfma_f32_16x16x32_bf16(af[i], bfr[j], acc[i][j], 0, 0, 0);
        }
    }

#pragma unroll
    for (int i = 0; i < 2; ++i) {
#pragma unroll
        for (int r = 0; r < 4; ++r) {
            int m = m0 + wrow + i * 16 + quad * 4 + r;
#pragma unroll
            for (int j = 0; j < 4; ++j) {
                int n = n0 + wcol + j * 16 + l16;
                size_t idx = (size_t)m * N + n;
                outp[idx] = acc[i][j][r] + bias[n] + res[idx];
            }
        }
    }
}

// ---------------------------------------------------------------- flash attention v2
__global__ __launch_bounds__(256)
void attn_kernel(const unsigned short* __restrict__ qp,
                 const unsigned short* __restrict__ kp,
                 const unsigned short* __restrict__ vt,
                 unsigned short* __restrict__ op,
                 int qstride, int kstride, int causal)
{
    __shared__ unsigned short lK[64 * 72];
    __shared__ unsigned short lV[64 * 72];
    __shared__ unsigned short lP[4][16 * 72];

    const int tid = threadIdx.x;
    const int wave = tid >> 6, lane = tid & 63;
    const int quad = lane >> 4, l16 = lane & 15;
    const int bh = blockIdx.y, b = bh >> 4, h = bh & 15;
    const int qtile = causal ? (gridDim.x - 1 - blockIdx.x) : blockIdx.x;
    const int q0 = qtile * 64;
    const size_t rowbase = (size_t)b * TT;
    const int hoff = h * 64;
    const unsigned short* vbase = vt + (size_t)bh * 64 * TT;

    bf16x8 qf[2];
    {
        int qrow = q0 + wave * 16 + l16;
        const unsigned short* qrp = qp + (rowbase + qrow) * (size_t)qstride + hoff;
        qf[0] = *(const bf16x8*)(qrp + quad * 8);
        qf[1] = *(const bf16x8*)(qrp + 32 + quad * 8);
    }

    f32x4 oacc[4];
#pragma unroll
    for (int jd = 0; jd < 4; ++jd)
#pragma unroll
        for (int r = 0; r < 4; ++r) oacc[jd][r] = 0.f;
    float mrun = -1e30f, lrun = 0.f;

    const int nkt = causal ? (qtile + 1) : (TT / 64);
    for (int kt = 0; kt < nkt; ++kt) {
        __syncthreads();
#pragma unroll
        for (int it = 0; it < 2; ++it) {
            int c = it * 256 + tid;
            int r8 = c >> 3, cc = c & 7;
            *(bf16x8*)&lK[r8 * 72 + cc * 8] =
                *(const bf16x8*)(kp + (rowbase + kt * 64 + r8) * (size_t)kstride + hoff + cc * 8);
            *(bf16x8*)&lV[r8 * 72 + cc * 8] =
                *(const bf16x8*)(vbase + (size_t)r8 * TT + kt * 64 + cc * 8);
        }
        __syncthreads();

        f32x4 s[4];
#pragma unroll
        for (int i = 0; i < 4; ++i)
#pragma unroll
            for (int r = 0; r < 4; ++r) s[i][r] = 0.f;
#pragma unroll
        for (int kk = 0; kk < 2; ++kk) {
            bf16x8 kf[4];
#pragma unroll
            for (int i = 0; i < 4; ++i)
                kf[i] = *(const bf16x8*)&lK[(i * 16 + l16) * 72 + kk * 32 + quad * 8];
#pragma unroll
            for (int i = 0; i < 4; ++i)
                s[i] = __builtin_amdgcn_mfma_f32_16x16x32_bf16(kf[i], qf[kk], s[i], 0, 0, 0);
        }

        const int qg = q0 + wave * 16 + l16;
        const bool domask = (causal != 0) && (kt == qtile);
        float mloc = -1e30f;
#pragma unroll
        for (int i = 0; i < 4; ++i)
#pragma unroll
            for (int r = 0; r < 4; ++r) {
                float v = s[i][r] * 0.125f;
                if (domask) {
                    int kg = kt * 64 + i * 16 + quad * 4 + r;
                    if (kg > qg) v = -1e30f;
                }
                s[i][r] = v;
                mloc = fmaxf(mloc, v);
            }
        mloc = fmaxf(mloc, __shfl_xor(mloc, 16, 64));
        mloc = fmaxf(mloc, __shfl_xor(mloc, 32, 64));
        float mn = fmaxf(mrun, mloc);
        float alpha = __expf(mrun - mn);
        mrun = mn;
        float ls = 0.f;
#pragma unroll
        for (int i = 0; i < 4; ++i)
#pragma unroll
            for (int r = 0; r < 4; ++r) {
                float p = __expf(s[i][r] - mn);
                s[i][r] = p;
                ls += p;
            }
        ls += __shfl_xor(ls, 16, 64);
        ls += __shfl_xor(ls, 32, 64);
        lrun = lrun * alpha + ls;

        float arow[4];
#pragma unroll
        for (int r = 0; r < 4; ++r)
            arow[r] = __shfl(alpha, quad * 4 + r, 64);
#pragma unroll
        for (int jd = 0; jd < 4; ++jd)
#pragma unroll
            for (int r = 0; r < 4; ++r) oacc[jd][r] *= arow[r];

        unsigned short* pw = lP[wave];
#pragma unroll
        for (int i = 0; i < 4; ++i) {
            ushort4 pk;
            pk.x = f2bf(s[i][0]); pk.y = f2bf(s[i][1]);
            pk.z = f2bf(s[i][2]); pk.w = f2bf(s[i][3]);
            *(ushort4*)&pw[l16 * 72 + i * 16 + quad * 4] = pk;
        }

#pragma unroll
        for (int kk = 0; kk < 2; ++kk) {
            bf16x8 pf = *(const bf16x8*)&pw[l16 * 72 + kk * 32 + quad * 8];
            bf16x8 vf[4];
#pragma unroll
            for (int jd = 0; jd < 4; ++jd)
                vf[jd] = *(const bf16x8*)&lV[(jd * 16 + l16) * 72 + kk * 32 + quad * 8];
#pragma unroll
            for (int jd = 0; jd < 4; ++jd)
                oacc[jd] = __builtin_amdgcn_mfma_f32_16x16x32_bf16(pf, vf[jd], oacc[jd], 0, 0, 0);
        }
    }

    float ir[4];
#pragma unroll
    for (int r = 0; r < 4; ++r)
        ir[r] = 1.f / __shfl(lrun, quad * 4 + r, 64);
#pragma unroll
    for (int r = 0; r < 4; ++r) {
        int qg = q0 + wave * 16 + quad * 4 + r;
        unsigned short* orow = op + (rowbase + qg) * (size_t)1024 + hoff;
#pragma unroll
        for (int jd = 0; jd < 4; ++jd)
            orow[jd * 16 + l16] = f2bf(oacc[jd][r] * ir[r]);
    }
}

// ---------------------------------------------------------------- launch
extern "C" void kernel_launch(void* const* d_in, const int* in_sizes, int n_in,
                              void* d_out, int out_size, void* d_ws, size_t ws_size,
                              hipStream_t stream)
{
    const float* x     = (const float*)d_in[0];
    const float* ctx   = (const float*)d_in[1];
    const float* ln1_g = (const float*)d_in[2];
    const float* ln1_b = (const float*)d_in[3];
    const float* qkv_w = (const float*)d_in[4];
    const float* qkv_b = (const float*)d_in[5];
    const float* aow   = (const float*)d_in[6];
    const float* aob   = (const float*)d_in[7];
    const float* lnc_g = (const float*)d_in[8];
    const float* lnc_b = (const float*)d_in[9];
    const float* q_w   = (const float*)d_in[10];
    const float* q_b   = (const float*)d_in[11];
    const float* kv_w  = (const float*)d_in[12];
    const float* kv_b  = (const float*)d_in[13];
    const float* cow   = (const float*)d_in[14];
    const float* cob   = (const float*)d_in[15];
    const float* ln2_g = (const float*)d_in[16];
    const float* ln2_b = (const float*)d_in[17];
    const float* f1w   = (const float*)d_in[18];
    const float* f1b   = (const float*)d_in[19];
    const float* f2w   = (const float*)d_in[20];
    const float* f2b   = (const float*)d_in[21];

    char* ws = (char*)d_ws;
    size_t off = 0;
    auto alloc = [&](size_t bytes) {
        char* p = ws + off;
        off += (bytes + 255) & ~(size_t)255;
        return p;
    };

    unsigned short* WtQKV = (unsigned short*)alloc((size_t)3072 * 1024 * 2);
    unsigned short* WtAO  = (unsigned short*)alloc((size_t)1024 * 1024 * 2);
    unsigned short* WtQ   = (unsigned short*)alloc((size_t)1024 * 1024 * 2);
    unsigned short* WtKV  = (unsigned short*)alloc((size_t)2048 * 1024 * 2);
    unsigned short* WtCO  = (unsigned short*)alloc((size_t)1024 * 1024 * 2);
    unsigned short* WtF1  = (unsigned short*)alloc((size_t)4096 * 1024 * 2);
    unsigned short* WtF2  = (unsigned short*)alloc((size_t)1024 * 4096 * 2);
    unsigned short* hA    = (unsigned short*)alloc((size_t)BT * 1024 * 2);
    unsigned short* ctxb  = (unsigned short*)alloc((size_t)BT * 1024 * 2);
    unsigned short* qkvb  = (unsigned short*)alloc((size_t)BT * 3072 * 2);
    unsigned short* o1    = (unsigned short*)alloc((size_t)BT * 1024 * 2);
    float*          x1    = (float*)alloc((size_t)BT * 1024 * 4);
    unsigned short* qb    = (unsigned short*)alloc((size_t)BT * 1024 * 2);
    unsigned short* kvb   = (unsigned short*)alloc((size_t)BT * 2048 * 2);
    unsigned short* o2    = (unsigned short*)alloc((size_t)BT * 1024 * 2);
    float*          x2    = (float*)alloc((size_t)BT * 1024 * 4);
    unsigned short* mid   = (unsigned short*)alloc((size_t)BT * 4096 * 2);
    unsigned short* vT1   = (unsigned short*)alloc((size_t)BT * 1024 * 2);
    unsigned short* vT2   = (unsigned short*)alloc((size_t)BT * 1024 * 2);

    float* partials = (float*)qkvb;   // dead by FFN2 time; 67 MB fits in 75.5 MB region

    TransJobs J;
    J.W[0]=qkv_w; J.Wt[0]=WtQKV; J.K[0]=1024; J.N[0]=3072;
    J.W[1]=aow;   J.Wt[1]=WtAO;  J.K[1]=1024; J.N[1]=1024;
    J.W[2]=q_w;   J.Wt[2]=WtQ;   J.K[2]=1024; J.N[2]=1024;
    J.W[3]=kv_w;  J.Wt[3]=WtKV;  J.K[3]=1024; J.N[3]=2048;
    J.W[4]=cow;   J.Wt[4]=WtCO;  J.K[4]=1024; J.N[4]=1024;
    J.W[5]=f1w;   J.Wt[5]=WtF1;  J.K[5]=1024; J.N[5]=4096;
    J.W[6]=f2w;   J.Wt[6]=WtF2;  J.K[6]=4096; J.N[6]=1024;
    int acc = 0;
    for (int j = 0; j < 7; ++j) {
        J.start[j] = acc;
        acc += (J.N[j] / 32) * (J.K[j] / 32);
    }
    J.start[7] = acc;

    dim3 tb(32, 8);
    transpose_all<<<acc, tb, 0, stream>>>(J);
    cast_bf16<<<BT * 1024 / 4 / 256, 256, 0, stream>>>(ctx, ctxb);

    // self-attention block
    ln_kernel<<<BT, 256, 0, stream>>>(x, ln1_g, ln1_b, hA);
    gemm_bt<0><<<dim3(3072/128, BT/128), 256, 0, stream>>>(hA, WtQKV, qkv_b, nullptr, qkvb, BT, 3072, 1024);
    transpose_v<<<dim3(2, TT/32, 64), tb, 0, stream>>>(qkvb + 2048, vT1, 3072);
    attn_kernel<<<dim3(TT/64, 64), 256, 0, stream>>>(qkvb, qkvb + 1024, vT1, o1, 3072, 3072, 1);
    gemm_small2<<<dim3(1024/128, BT/64), 256, 0, stream>>>(o1, WtAO, aob, x, x1, BT, 1024, 1024);

    // cross-attention block
    ln_kernel<<<BT, 256, 0, stream>>>(x1, lnc_g, lnc_b, hA);
    gemm_dual<<<dim3(1024/128 + 2048/128, BT/128), 256, 0, stream>>>(
        hA, WtQ, q_b, qb, 1024, 1024/128,
        ctxb, WtKV, kv_b, kvb, 2048, 1024);
    transpose_v<<<dim3(2, TT/32, 64), tb, 0, stream>>>(kvb + 1024, vT2, 2048);
    attn_kernel<<<dim3(TT/64, 64), 256, 0, stream>>>(qb, kvb, vT2, o2, 1024, 2048, 0);
    gemm_small2<<<dim3(1024/128, BT/64), 256, 0, stream>>>(o2, WtCO, cob, x1, x2, BT, 1024, 1024);

    // FFN block
    ln_kernel<<<BT, 256, 0, stream>>>(x2, ln2_g, ln2_b, hA);
    gemm_bt<1><<<dim3(4096/128, BT/128), 256, 0, stream>>>(hA, WtF1, f1b, nullptr, mid, BT, 4096, 1024);
    gemm_splitk<<<dim3(1024/128, BT/128, 4), 256, 0, stream>>>(mid, WtF2, partials, BT, 1024, 4096, 1024);
    reduce4<<<BT * 1024 / 4 / 256, 256, 0, stream>>>(partials, f2b, x2, (float*)d_out, BT * 1024);
}

// Round 5
// 537.294 us; speedup vs baseline: 1.3243x; 1.0071x over previous
//
#include <hip/hip_runtime.h>
#include <hip/hip_bf16.h>

#define BT 4096        // B*T rows
#define TT 1024        // T
#define HN 16          // heads

typedef __attribute__((ext_vector_type(8))) short bf16x8;
typedef __attribute__((ext_vector_type(4))) float f32x4;

__device__ __forceinline__ unsigned short f2bf(float f) {
    unsigned u = __builtin_bit_cast(unsigned, f);
    unsigned r = (u + 0x7fffu + ((u >> 16) & 1u)) >> 16;
    return (unsigned short)r;
}

__device__ __forceinline__ void g2l16(const void* g, void* l) {
    __builtin_amdgcn_global_load_lds(
        (__attribute__((address_space(1))) void*)(g),
        (__attribute__((address_space(3))) void*)(l), 16, 0, 0);
}

// tanh-approx gelu via hardware exp; overflow-safe
__device__ __forceinline__ float gelu_f(float v) {
    float t = v * (0.7978845608f + 0.0356774081f * v * v);
    float e = __expf(2.f * t);
    float th = 1.f - 2.f / (e + 1.f);
    return 0.5f * v * (1.f + th);
}

// ---------------------------------------------------------------- fused weight transpose
struct TransJobs {
    const float* W[7];
    unsigned short* Wt[7];
    int K[7], N[7];
    int start[8];
};

__global__ __launch_bounds__(256)
void transpose_all(TransJobs J)
{
    __shared__ float tile[32][33];
    int bx = blockIdx.x;
    int j = 0;
#pragma unroll
    for (int t = 0; t < 7; ++t)
        if (bx >= J.start[t + 1]) j = t + 1;
    int t = bx - J.start[j];
    int K = J.K[j], N = J.N[j];
    int ntx = N >> 5;
    int n0 = (t % ntx) * 32, k0 = (t / ntx) * 32;
    const float* W = J.W[j];
    unsigned short* Wt = J.Wt[j];
    int tx = threadIdx.x, ty = threadIdx.y;
#pragma unroll
    for (int i = ty; i < 32; i += 8)
        tile[i][tx] = W[(size_t)(k0 + i) * N + n0 + tx];
    __syncthreads();
#pragma unroll
    for (int i = ty; i < 32; i += 8)
        Wt[(size_t)(n0 + i) * K + k0 + tx] = f2bf(tile[tx][i]);
}

// ---------------------------------------------------------------- V transpose (bf16)
__global__ __launch_bounds__(256)
void transpose_v(const unsigned short* __restrict__ v, unsigned short* __restrict__ vt,
                 int stride)
{
    __shared__ unsigned short tile[32][33];
    int d0 = blockIdx.x * 32, t0 = blockIdx.y * 32, bh = blockIdx.z;
    int b = bh >> 4, h = bh & 15;
    int tx = threadIdx.x, ty = threadIdx.y;
#pragma unroll
    for (int i = ty; i < 32; i += 8)
        tile[i][tx] = v[((size_t)b * TT + t0 + i) * stride + h * 64 + d0 + tx];
    __syncthreads();
#pragma unroll
    for (int i = ty; i < 32; i += 8)
        vt[((size_t)bh * 64 + d0 + i) * TT + t0 + tx] = tile[tx][i];
}

// ---------------------------------------------------------------- f32 -> bf16 cast
__global__ __launch_bounds__(256)
void cast_bf16(const float* __restrict__ in, unsigned short* __restrict__ out)
{
    int i = blockIdx.x * 256 + threadIdx.x;
    float4 v = ((const float4*)in)[i];
    ushort4 o;
    o.x = f2bf(v.x); o.y = f2bf(v.y); o.z = f2bf(v.z); o.w = f2bf(v.w);
    ((ushort4*)out)[i] = o;
}

// ---------------------------------------------------------------- LayerNorm (C=1024)
__global__ __launch_bounds__(256)
void ln_kernel(const float* __restrict__ x, const float* __restrict__ g,
               const float* __restrict__ bta, unsigned short* __restrict__ out)
{
    __shared__ float red[8];
    int row = blockIdx.x;
    const float* xr = x + (size_t)row * 1024;
    float4 v = ((const float4*)xr)[threadIdx.x];
    float s = v.x + v.y + v.z + v.w;
    float q = v.x*v.x + v.y*v.y + v.z*v.z + v.w*v.w;
#pragma unroll
    for (int m = 1; m < 64; m <<= 1) {
        s += __shfl_xor(s, m, 64);
        q += __shfl_xor(q, m, 64);
    }
    int wave = threadIdx.x >> 6;
    if ((threadIdx.x & 63) == 0) { red[wave] = s; red[4 + wave] = q; }
    __syncthreads();
    s = red[0] + red[1] + red[2] + red[3];
    q = red[4] + red[5] + red[6] + red[7];
    float mean = s * (1.f / 1024.f);
    float var  = q * (1.f / 1024.f) - mean * mean;
    float rstd = rsqrtf(var + 1e-5f);
    float4 gv = ((const float4*)g)[threadIdx.x];
    float4 bv = ((const float4*)bta)[threadIdx.x];
    ushort4 o;
    o.x = f2bf((v.x - mean) * rstd * gv.x + bv.x);
    o.y = f2bf((v.y - mean) * rstd * gv.y + bv.y);
    o.z = f2bf((v.z - mean) * rstd * gv.z + bv.z);
    o.w = f2bf((v.w - mean) * rstd * gv.w + bv.w);
    ((ushort4*)(out + (size_t)row * 1024))[threadIdx.x] = o;
}

// ---------------------------------------------------------------- GEMM core (128x128 tile)
// XOR-swizzled LDS: global chunk kc lives at slot kc^(row&7); row stride 64 elem.
// MODE 0: out bf16   MODE 1: out bf16, gelu   MODE 2: out f32, + res
// MODE 3: out f32 partial (no bias)
template<int MODE>
__device__ __forceinline__
void gemm_core(unsigned short* lA, unsigned short* lB,
               const unsigned short* __restrict__ A,
               const unsigned short* __restrict__ Bt,
               const float* __restrict__ bias,
               const float* __restrict__ res,
               void* __restrict__ outp,
               int N, int K, int m0, int n0, int kbeg, int kend)
{
    const int tid = threadIdx.x;
    const int wave = tid >> 6, lane = tid & 63;
    const int quad = lane >> 4, l16 = lane & 15;
    const int sw = l16 & 7;
    const int wrow = (wave >> 1) * 64, wcol = (wave & 1) * 64;

    f32x4 acc[4][4];
#pragma unroll
    for (int i = 0; i < 4; ++i)
#pragma unroll
        for (int j = 0; j < 4; ++j)
#pragma unroll
            for (int r = 0; r < 4; ++r) acc[i][j][r] = 0.f;

    for (int k0 = kbeg; k0 < kend; k0 += 64) {
        __syncthreads();
#pragma unroll
        for (int it = 0; it < 4; ++it) {
            int chunk = it * 256 + tid;
            int row = chunk >> 3, slot = chunk & 7;
            int kc = slot ^ (row & 7);                 // swizzled source chunk
            g2l16(A  + (size_t)(m0 + row) * K + k0 + kc * 8, &lA[chunk * 8]);
            g2l16(Bt + (size_t)(n0 + row) * K + k0 + kc * 8, &lB[chunk * 8]);
        }
        __syncthreads();
#pragma unroll
        for (int kk = 0; kk < 64; kk += 32) {
            const int gc = (kk >> 3) + quad;           // global chunk 0..7
            const int sl = (gc ^ sw) * 8;              // swizzled slot (elems)
            bf16x8 af[4], bfr[4];
#pragma unroll
            for (int i = 0; i < 4; ++i)
                af[i] = *(const bf16x8*)&lA[(wrow + i * 16 + l16) * 64 + sl];
#pragma unroll
            for (int j = 0; j < 4; ++j)
                bfr[j] = *(const bf16x8*)&lB[(wcol + j * 16 + l16) * 64 + sl];
#pragma unroll
            for (int i = 0; i < 4; ++i)
#pragma unroll
                for (int j = 0; j < 4; ++j)
                    acc[i][j] = __builtin_amdgcn_mfma_f32_16x16x32_bf16(af[i], bfr[j], acc[i][j], 0, 0, 0);
        }
    }

#pragma unroll
    for (int i = 0; i < 4; ++i) {
#pragma unroll
        for (int r = 0; r < 4; ++r) {
            int m = m0 + wrow + i * 16 + quad * 4 + r;
#pragma unroll
            for (int j = 0; j < 4; ++j) {
                int n = n0 + wcol + j * 16 + l16;
                float v = acc[i][j][r];
                if (MODE != 3) v += bias[n];
                if (MODE == 1) v = gelu_f(v);
                size_t idx = (size_t)m * N + n;
                if (MODE == 2) ((float*)outp)[idx] = v + res[idx];
                else if (MODE == 3) ((float*)outp)[idx] = v;
                else ((unsigned short*)outp)[idx] = f2bf(v);
            }
        }
    }
}

template<int MODE>
__global__ __launch_bounds__(256)
void gemm_bt(const unsigned short* __restrict__ A,
             const unsigned short* __restrict__ Bt,
             const float* __restrict__ bias,
             const float* __restrict__ res,
             void* __restrict__ outp,
             int M, int N, int K)
{
    __shared__ unsigned short lA[128 * 64];
    __shared__ unsigned short lB[128 * 64];
    gemm_core<MODE>(lA, lB, A, Bt, bias, res, outp, N, K,
                    blockIdx.y * 128, blockIdx.x * 128, 0, K);
}

// fused q + kv GEMM
__global__ __launch_bounds__(256)
void gemm_dual(const unsigned short* __restrict__ A1, const unsigned short* __restrict__ B1,
               const float* __restrict__ b1, unsigned short* __restrict__ o1p, int N1, int nbx1,
               const unsigned short* __restrict__ A2, const unsigned short* __restrict__ B2,
               const float* __restrict__ b2, unsigned short* __restrict__ o2p, int N2,
               int K)
{
    __shared__ unsigned short lA[128 * 64];
    __shared__ unsigned short lB[128 * 64];
    int bx = blockIdx.x;
    if (bx < nbx1)
        gemm_core<0>(lA, lB, A1, B1, b1, nullptr, o1p, N1, K,
                     blockIdx.y * 128, bx * 128, 0, K);
    else
        gemm_core<0>(lA, lB, A2, B2, b2, nullptr, o2p, N2, K,
                     blockIdx.y * 128, (bx - nbx1) * 128, 0, K);
}

// split-K GEMM: grid.z = 2 slices of K/2, fp32 partials, no bias
__global__ __launch_bounds__(256)
void gemm_splitk(const unsigned short* __restrict__ A,
                 const unsigned short* __restrict__ Bt,
                 float* __restrict__ part,
                 int M, int N, int K, int kslice)
{
    __shared__ unsigned short lA[128 * 64];
    __shared__ unsigned short lB[128 * 64];
    int kz = blockIdx.z;
    gemm_core<3>(lA, lB, A, Bt, nullptr, nullptr,
                 part + (size_t)kz * M * N, N, K,
                 blockIdx.y * 128, blockIdx.x * 128,
                 kz * kslice, (kz + 1) * kslice);
}

// reduce 2 partials + bias + res -> f32 out
__global__ __launch_bounds__(256)
void reduce2(const float* __restrict__ part, const float* __restrict__ bias,
             const float* __restrict__ res, float* __restrict__ out, int MN)
{
    int i = blockIdx.x * 256 + threadIdx.x;
    const float4* p = (const float4*)part;
    int q = MN >> 2;
    float4 a = p[i], b = p[i + q];
    float4 bs = ((const float4*)bias)[i & 255];
    float4 rr = ((const float4*)res)[i];
    float4 o;
    o.x = a.x + b.x + bs.x + rr.x;
    o.y = a.y + b.y + bs.y + rr.y;
    o.z = a.z + b.z + bs.z + rr.z;
    o.w = a.w + b.w + bs.w + rr.w;
    ((float4*)out)[i] = o;
}

// ---------------------------------------------------------------- small GEMM (64x128 tile)
__global__ __launch_bounds__(256)
void gemm_small2(const unsigned short* __restrict__ A,
                 const unsigned short* __restrict__ Bt,
                 const float* __restrict__ bias,
                 const float* __restrict__ res,
                 float* __restrict__ outp,
                 int M, int N, int K)
{
    __shared__ unsigned short lA[64 * 64];
    __shared__ unsigned short lB[128 * 64];
    const int tid = threadIdx.x;
    const int wave = tid >> 6, lane = tid & 63;
    const int quad = lane >> 4, l16 = lane & 15;
    const int sw = l16 & 7;
    const int m0 = blockIdx.y * 64, n0 = blockIdx.x * 128;
    const int wrow = (wave >> 1) * 32, wcol = (wave & 1) * 64;

    f32x4 acc[2][4];
#pragma unroll
    for (int i = 0; i < 2; ++i)
#pragma unroll
        for (int j = 0; j < 4; ++j)
#pragma unroll
            for (int r = 0; r < 4; ++r) acc[i][j][r] = 0.f;

    for (int k0 = 0; k0 < K; k0 += 64) {
        __syncthreads();
#pragma unroll
        for (int it = 0; it < 6; ++it) {
            int chunk = it * 256 + tid;
            if (chunk < 512) {
                int row = chunk >> 3, slot = chunk & 7;
                int kc = slot ^ (row & 7);
                g2l16(A + (size_t)(m0 + row) * K + k0 + kc * 8, &lA[chunk * 8]);
            } else {
                int cb = chunk - 512;
                int row = cb >> 3, slot = cb & 7;
                int kc = slot ^ (row & 7);
                g2l16(Bt + (size_t)(n0 + row) * K + k0 + kc * 8, &lB[cb * 8]);
            }
        }
        __syncthreads();
#pragma unroll
        for (int kk = 0; kk < 64; kk += 32) {
            const int gc = (kk >> 3) + quad;
            const int sl = (gc ^ sw) * 8;
            bf16x8 af[2], bfr[4];
#pragma unroll
            for (int i = 0; i < 2; ++i)
                af[i] = *(const bf16x8*)&lA[(wrow + i * 16 + l16) * 64 + sl];
#pragma unroll
            for (int j = 0; j < 4; ++j)
                bfr[j] = *(const bf16x8*)&lB[(wcol + j * 16 + l16) * 64 + sl];
#pragma unroll
            for (int i = 0; i < 2; ++i)
#pragma unroll
                for (int j = 0; j < 4; ++j)
                    acc[i][j] = __builtin_amdgcn_mfma_f32_16x16x32_bf16(af[i], bfr[j], acc[i][j], 0, 0, 0);
        }
    }

#pragma unroll
    for (int i = 0; i < 2; ++i) {
#pragma unroll
        for (int r = 0; r < 4; ++r) {
            int m = m0 + wrow + i * 16 + quad * 4 + r;
#pragma unroll
            for (int j = 0; j < 4; ++j) {
                int n = n0 + wcol + j * 16 + l16;
                size_t idx = (size_t)m * N + n;
                outp[idx] = acc[i][j][r] + bias[n] + res[idx];
            }
        }
    }
}

// ---------------------------------------------------------------- flash attention v2
__global__ __launch_bounds__(256)
void attn_kernel(const unsigned short* __restrict__ qp,
                 const unsigned short* __restrict__ kp,
                 const unsigned short* __restrict__ vt,
                 unsigned short* __restrict__ op,
                 int qstride, int kstride, int causal)
{
    __shared__ unsigned short lK[64 * 72];
    __shared__ unsigned short lV[64 * 72];
    __shared__ unsigned short lP[4][16 * 72];

    const int tid = threadIdx.x;
    const int wave = tid >> 6, lane = tid & 63;
    const int quad = lane >> 4, l16 = lane & 15;
    const int bh = blockIdx.y, b = bh >> 4, h = bh & 15;
    const int qtile = causal ? (gridDim.x - 1 - blockIdx.x) : blockIdx.x;
    const int q0 = qtile * 64;
    const size_t rowbase = (size_t)b * TT;
    const int hoff = h * 64;
    const unsigned short* vbase = vt + (size_t)bh * 64 * TT;

    bf16x8 qf[2];
    {
        int qrow = q0 + wave * 16 + l16;
        const unsigned short* qrp = qp + (rowbase + qrow) * (size_t)qstride + hoff;
        qf[0] = *(const bf16x8*)(qrp + quad * 8);
        qf[1] = *(const bf16x8*)(qrp + 32 + quad * 8);
    }

    f32x4 oacc[4];
#pragma unroll
    for (int jd = 0; jd < 4; ++jd)
#pragma unroll
        for (int r = 0; r < 4; ++r) oacc[jd][r] = 0.f;
    float mrun = -1e30f, lrun = 0.f;

    const int nkt = causal ? (qtile + 1) : (TT / 64);
    for (int kt = 0; kt < nkt; ++kt) {
        __syncthreads();
#pragma unroll
        for (int it = 0; it < 2; ++it) {
            int c = it * 256 + tid;
            int r8 = c >> 3, cc = c & 7;
            *(bf16x8*)&lK[r8 * 72 + cc * 8] =
                *(const bf16x8*)(kp + (rowbase + kt * 64 + r8) * (size_t)kstride + hoff + cc * 8);
            *(bf16x8*)&lV[r8 * 72 + cc * 8] =
                *(const bf16x8*)(vbase + (size_t)r8 * TT + kt * 64 + cc * 8);
        }
        __syncthreads();

        f32x4 s[4];
#pragma unroll
        for (int i = 0; i < 4; ++i)
#pragma unroll
            for (int r = 0; r < 4; ++r) s[i][r] = 0.f;
#pragma unroll
        for (int kk = 0; kk < 2; ++kk) {
            bf16x8 kf[4];
#pragma unroll
            for (int i = 0; i < 4; ++i)
                kf[i] = *(const bf16x8*)&lK[(i * 16 + l16) * 72 + kk * 32 + quad * 8];
#pragma unroll
            for (int i = 0; i < 4; ++i)
                s[i] = __builtin_amdgcn_mfma_f32_16x16x32_bf16(kf[i], qf[kk], s[i], 0, 0, 0);
        }

        const int qg = q0 + wave * 16 + l16;
        const bool domask = (causal != 0) && (kt == qtile);
        float mloc = -1e30f;
#pragma unroll
        for (int i = 0; i < 4; ++i)
#pragma unroll
            for (int r = 0; r < 4; ++r) {
                float v = s[i][r] * 0.125f;
                if (domask) {
                    int kg = kt * 64 + i * 16 + quad * 4 + r;
                    if (kg > qg) v = -1e30f;
                }
                s[i][r] = v;
                mloc = fmaxf(mloc, v);
            }
        mloc = fmaxf(mloc, __shfl_xor(mloc, 16, 64));
        mloc = fmaxf(mloc, __shfl_xor(mloc, 32, 64));
        float mn = fmaxf(mrun, mloc);
        float alpha = __expf(mrun - mn);
        mrun = mn;
        float ls = 0.f;
#pragma unroll
        for (int i = 0; i < 4; ++i)
#pragma unroll
            for (int r = 0; r < 4; ++r) {
                float p = __expf(s[i][r] - mn);
                s[i][r] = p;
                ls += p;
            }
        ls += __shfl_xor(ls, 16, 64);
        ls += __shfl_xor(ls, 32, 64);
        lrun = lrun * alpha + ls;

        float arow[4];
#pragma unroll
        for (int r = 0; r < 4; ++r)
            arow[r] = __shfl(alpha, quad * 4 + r, 64);
#pragma unroll
        for (int jd = 0; jd < 4; ++jd)
#pragma unroll
            for (int r = 0; r < 4; ++r) oacc[jd][r] *= arow[r];

        unsigned short* pw = lP[wave];
#pragma unroll
        for (int i = 0; i < 4; ++i) {
            ushort4 pk;
            pk.x = f2bf(s[i][0]); pk.y = f2bf(s[i][1]);
            pk.z = f2bf(s[i][2]); pk.w = f2bf(s[i][3]);
            *(ushort4*)&pw[l16 * 72 + i * 16 + quad * 4] = pk;
        }

#pragma unroll
        for (int kk = 0; kk < 2; ++kk) {
            bf16x8 pf = *(const bf16x8*)&pw[l16 * 72 + kk * 32 + quad * 8];
            bf16x8 vf[4];
#pragma unroll
            for (int jd = 0; jd < 4; ++jd)
                vf[jd] = *(const bf16x8*)&lV[(jd * 16 + l16) * 72 + kk * 32 + quad * 8];
#pragma unroll
            for (int jd = 0; jd < 4; ++jd)
                oacc[jd] = __builtin_amdgcn_mfma_f32_16x16x32_bf16(pf, vf[jd], oacc[jd], 0, 0, 0);
        }
    }

    float ir[4];
#pragma unroll
    for (int r = 0; r < 4; ++r)
        ir[r] = 1.f / __shfl(lrun, quad * 4 + r, 64);
#pragma unroll
    for (int r = 0; r < 4; ++r) {
        int qg = q0 + wave * 16 + quad * 4 + r;
        unsigned short* orow = op + (rowbase + qg) * (size_t)1024 + hoff;
#pragma unroll
        for (int jd = 0; jd < 4; ++jd)
            orow[jd * 16 + l16] = f2bf(oacc[jd][r] * ir[r]);
    }
}

// ---------------------------------------------------------------- launch
extern "C" void kernel_launch(void* const* d_in, const int* in_sizes, int n_in,
                              void* d_out, int out_size, void* d_ws, size_t ws_size,
                              hipStream_t stream)
{
    const float* x     = (const float*)d_in[0];
    const float* ctx   = (const float*)d_in[1];
    const float* ln1_g = (const float*)d_in[2];
    const float* ln1_b = (const float*)d_in[3];
    const float* qkv_w = (const float*)d_in[4];
    const float* qkv_b = (const float*)d_in[5];
    const float* aow   = (const float*)d_in[6];
    const float* aob   = (const float*)d_in[7];
    const float* lnc_g = (const float*)d_in[8];
    const float* lnc_b = (const float*)d_in[9];
    const float* q_w   = (const float*)d_in[10];
    const float* q_b   = (const float*)d_in[11];
    const float* kv_w  = (const float*)d_in[12];
    const float* kv_b  = (const float*)d_in[13];
    const float* cow   = (const float*)d_in[14];
    const float* cob   = (const float*)d_in[15];
    const float* ln2_g = (const float*)d_in[16];
    const float* ln2_b = (const float*)d_in[17];
    const float* f1w   = (const float*)d_in[18];
    const float* f1b   = (const float*)d_in[19];
    const float* f2w   = (const float*)d_in[20];
    const float* f2b   = (const float*)d_in[21];

    char* ws = (char*)d_ws;
    size_t off = 0;
    auto alloc = [&](size_t bytes) {
        char* p = ws + off;
        off += (bytes + 255) & ~(size_t)255;
        return p;
    };

    unsigned short* WtQKV = (unsigned short*)alloc((size_t)3072 * 1024 * 2);
    unsigned short* WtAO  = (unsigned short*)alloc((size_t)1024 * 1024 * 2);
    unsigned short* WtQ   = (unsigned short*)alloc((size_t)1024 * 1024 * 2);
    unsigned short* WtKV  = (unsigned short*)alloc((size_t)2048 * 1024 * 2);
    unsigned short* WtCO  = (unsigned short*)alloc((size_t)1024 * 1024 * 2);
    unsigned short* WtF1  = (unsigned short*)alloc((size_t)4096 * 1024 * 2);
    unsigned short* WtF2  = (unsigned short*)alloc((size_t)1024 * 4096 * 2);
    unsigned short* hA    = (unsigned short*)alloc((size_t)BT * 1024 * 2);
    unsigned short* ctxb  = (unsigned short*)alloc((size_t)BT * 1024 * 2);
    unsigned short* qkvb  = (unsigned short*)alloc((size_t)BT * 3072 * 2);
    unsigned short* o1    = (unsigned short*)alloc((size_t)BT * 1024 * 2);
    float*          x1    = (float*)alloc((size_t)BT * 1024 * 4);
    unsigned short* qb    = (unsigned short*)alloc((size_t)BT * 1024 * 2);
    unsigned short* kvb   = (unsigned short*)alloc((size_t)BT * 2048 * 2);
    unsigned short* o2    = (unsigned short*)alloc((size_t)BT * 1024 * 2);
    float*          x2    = (float*)alloc((size_t)BT * 1024 * 4);
    unsigned short* mid   = (unsigned short*)alloc((size_t)BT * 4096 * 2);
    unsigned short* vT1   = (unsigned short*)alloc((size_t)BT * 1024 * 2);
    unsigned short* vT2   = (unsigned short*)alloc((size_t)BT * 1024 * 2);

    float* partials = (float*)qkvb;   // dead by FFN2 time; 33.5 MB fits easily

    TransJobs J;
    J.W[0]=qkv_w; J.Wt[0]=WtQKV; J.K[0]=1024; J.N[0]=3072;
    J.W[1]=aow;   J.Wt[1]=WtAO;  J.K[1]=1024; J.N[1]=1024;
    J.W[2]=q_w;   J.Wt[2]=WtQ;   J.K[2]=1024; J.N[2]=1024;
    J.W[3]=kv_w;  J.Wt[3]=WtKV;  J.K[3]=1024; J.N[3]=2048;
    J.W[4]=cow;   J.Wt[4]=WtCO;  J.K[4]=1024; J.N[4]=1024;
    J.W[5]=f1w;   J.Wt[5]=WtF1;  J.K[5]=1024; J.N[5]=4096;
    J.W[6]=f2w;   J.Wt[6]=WtF2;  J.K[6]=4096; J.N[6]=1024;
    int acc = 0;
    for (int j = 0; j < 7; ++j) {
        J.start[j] = acc;
        acc += (J.N[j] / 32) * (J.K[j] / 32);
    }
    J.start[7] = acc;

    dim3 tb(32, 8);
    transpose_all<<<acc, tb, 0, stream>>>(J);
    cast_bf16<<<BT * 1024 / 4 / 256, 256, 0, stream>>>(ctx, ctxb);

    // self-attention block
    ln_kernel<<<BT, 256, 0, stream>>>(x, ln1_g, ln1_b, hA);
    gemm_bt<0><<<dim3(3072/128, BT/128), 256, 0, stream>>>(hA, WtQKV, qkv_b, nullptr, qkvb, BT, 3072, 1024);
    transpose_v<<<dim3(2, TT/32, 64), tb, 0, stream>>>(qkvb + 2048, vT1, 3072);
    attn_kernel<<<dim3(TT/64, 64), 256, 0, stream>>>(qkvb, qkvb + 1024, vT1, o1, 3072, 3072, 1);
    gemm_small2<<<dim3(1024/128, BT/64), 256, 0, stream>>>(o1, WtAO, aob, x, x1, BT, 1024, 1024);

    // cross-attention block
    ln_kernel<<<BT, 256, 0, stream>>>(x1, lnc_g, lnc_b, hA);
    gemm_dual<<<dim3(1024/128 + 2048/128, BT/128), 256, 0, stream>>>(
        hA, WtQ, q_b, qb, 1024, 1024/128,
        ctxb, WtKV, kv_b, kvb, 2048, 1024);
    transpose_v<<<dim3(2, TT/32, 64), tb, 0, stream>>>(kvb + 1024, vT2, 2048);
    attn_kernel<<<dim3(TT/64, 64), 256, 0, stream>>>(qb, kvb, vT2, o2, 1024, 2048, 0);
    gemm_small2<<<dim3(1024/128, BT/64), 256, 0, stream>>>(o2, WtCO, cob, x1, x2, BT, 1024, 1024);

    // FFN block
    ln_kernel<<<BT, 256, 0, stream>>>(x2, ln2_g, ln2_b, hA);
    gemm_bt<1><<<dim3(4096/128, BT/128), 256, 0, stream>>>(hA, WtF1, f1b, nullptr, mid, BT, 4096, 1024);
    gemm_splitk<<<dim3(1024/128, BT/128, 2), 256, 0, stream>>>(mid, WtF2, partials, BT, 1024, 4096, 2048);
    reduce2<<<BT * 1024 / 4 / 256, 256, 0, stream>>>(partials, f2b, x2, (float*)d_out, BT * 1024);
}